// Round 2
// baseline (1627.341 us; speedup 1.0000x reference)
//
#include <hip/hip_runtime.h>
#include <hip/hip_bf16.h>

#define NDOC 4
#define CL   512
#define DD   768
#define HH   12
#define EE   20
#define MM   4
#define PP   380
#define NPAIR 1520
#define LOUT 97

// ---------------------------------------------------------------------------
// Merged: blocks [0,320): eatt rows; blocks [320,400): glob rows.
// eatt[i,e,m,c] = mean over heads of attention[i,h,pos,c], pos=ms+1
//   (the reference pads a 513th column of zeros; indices never reach it, so we drop it)
// glob[i,e,d]   = logsumexp over M mentions of seq[i,pos,d]
__global__ __launch_bounds__(256) void k_prep(const float* __restrict__ att,
                                              const float* __restrict__ seq,
                                              const int* __restrict__ ms,
                                              float* __restrict__ eatt,
                                              float* __restrict__ glob)
{
    int b = blockIdx.x;
    if (b < NDOC*EE*MM) {
        int row = b;                       // i*EE*MM + e*MM + m
        int i = row / (EE*MM);
        int pos = ms[row] + 1;
        const float* base = att + ((size_t)i*HH)*CL*CL + (size_t)pos*CL;
        for (int c = threadIdx.x; c < CL; c += 256) {
            float s = 0.f;
            #pragma unroll
            for (int h = 0; h < HH; ++h) s += base[(size_t)h*CL*CL + c];
            eatt[(size_t)row*CL + c] = s * (1.0f/HH);
        }
    } else {
        int ie = b - NDOC*EE*MM;           // i*EE+e
        int i = ie / EE;
        const int* mp = ms + ie*MM;
        const float* sb = seq + (size_t)i*CL*DD;
        const float* r0 = sb + (size_t)(mp[0]+1)*DD;
        const float* r1 = sb + (size_t)(mp[1]+1)*DD;
        const float* r2 = sb + (size_t)(mp[2]+1)*DD;
        const float* r3 = sb + (size_t)(mp[3]+1)*DD;
        for (int d = threadIdx.x; d < DD; d += 256) {
            float a=r0[d], bb=r1[d], c=r2[d], e=r3[d];
            float mx = fmaxf(fmaxf(a,bb), fmaxf(c,e));
            float s = expf(a-mx)+expf(bb-mx)+expf(c-mx)+expf(e-mx);
            glob[(size_t)ie*DD + d] = mx + logf(s);
        }
    }
}

// Per pair: inline pair_hatt/pair_tatt (normalized), then
//   new_hs/new_ts -> qcat & hcat/tcat col0;  pa = normalized nh_att*nt_att (512 cols)
__global__ __launch_bounds__(256) void k_pairvec(const float* __restrict__ seq,
                                                 const float* __restrict__ eatt,
                                                 const int* __restrict__ ms,
                                                 const int* __restrict__ hts,
                                                 float* __restrict__ qcat,
                                                 float* __restrict__ hcat,
                                                 float* __restrict__ tcat,
                                                 float* __restrict__ pa)
{
    int g = blockIdx.x;
    int i = g / PP;
    int h = hts[2*g], t = hts[2*g+1];
    const float* eh = eatt + (size_t)(i*EE+h)*MM*CL;
    const float* et = eatt + (size_t)(i*EE+t)*MM*CL;
    int ph[MM], pt[MM];
    #pragma unroll
    for (int m=0;m<MM;++m){ ph[m]=ms[(i*EE+h)*MM+m]+1; pt[m]=ms[(i*EE+t)*MM+m]+1; }
    // pair weights (all threads compute identically from broadcast loads)
    float pH[MM], pT[MM]; float sh=0.f, st=0.f;
    #pragma unroll
    for (int m2=0; m2<MM; ++m2) {
        float s = 0.f, s2 = 0.f;
        #pragma unroll
        for (int m=0;m<MM;++m) { s += eh[m*CL + pt[m2]]; s2 += et[m*CL + ph[m2]]; }
        pH[m2] = s*0.25f;  sh += pH[m2];
        pT[m2] = s2*0.25f; st += pT[m2];
    }
    float rh = 1.f/(sh+1e-5f), rt = 1.f/(st+1e-5f);
    #pragma unroll
    for (int m=0;m<MM;++m){ pH[m]*=rh; pT[m]*=rt; }

    const float* sb = seq + (size_t)i*CL*DD;
    for (int d = threadIdx.x; d < DD; d += 256) {
        float nh = pT[0]*sb[(size_t)ph[0]*DD+d] + pT[1]*sb[(size_t)ph[1]*DD+d]
                 + pT[2]*sb[(size_t)ph[2]*DD+d] + pT[3]*sb[(size_t)ph[3]*DD+d];
        float nt = pH[0]*sb[(size_t)pt[0]*DD+d] + pH[1]*sb[(size_t)pt[1]*DD+d]
                 + pH[2]*sb[(size_t)pt[2]*DD+d] + pH[3]*sb[(size_t)pt[3]*DD+d];
        qcat[(size_t)g*1536 + d]      = nh;
        qcat[(size_t)g*1536 + DD + d] = nt;
        hcat[(size_t)g*2304 + d]      = nh;
        tcat[(size_t)g*2304 + d]      = nt;
    }
    float vv[2]; float lsum = 0.f;
    #pragma unroll
    for (int it=0; it<2; ++it) {
        int c = threadIdx.x + it*256;
        float na = pT[0]*eh[c] + pT[1]*eh[CL+c] + pT[2]*eh[2*CL+c] + pT[3]*eh[3*CL+c];
        float nb = pH[0]*et[c] + pH[1]*et[CL+c] + pH[2]*et[2*CL+c] + pH[3]*et[3*CL+c];
        vv[it] = na*nb; lsum += vv[it];
    }
    float tot = lsum;
    #pragma unroll
    for (int o=32;o;o>>=1) tot += __shfl_xor(tot, o);
    __shared__ float wsum[4];
    if ((threadIdx.x & 63)==0) wsum[threadIdx.x>>6] = tot;
    __syncthreads();
    float inv = 1.f/(wsum[0]+wsum[1]+wsum[2]+wsum[3] + 1e-5f);
    #pragma unroll
    for (int it=0; it<2; ++it)
        pa[(size_t)g*CL + threadIdx.x + it*256] = vv[it]*inv;
}

// edge[i,h,t,d] = relu(A[i,h,d] + B[i,t,d] + bm[d])
__global__ __launch_bounds__(256) void k_edge(const float* __restrict__ Ab,
                                              const float* __restrict__ Bb,
                                              const float* __restrict__ bm,
                                              float* __restrict__ edge)
{
    int iht = blockIdx.x;                  // i*400 + h*20 + t (1600)
    int i = iht/(EE*EE); int rem = iht%(EE*EE); int h = rem/EE; int tt = rem%EE;
    const float* a = Ab + (size_t)(i*EE+h)*DD;
    const float* b = Bb + (size_t)(i*EE+tt)*DD;
    float* e = edge + (size_t)iht*DD;
    for (int d=threadIdx.x; d<DD; d+=256)
        e[d] = fmaxf(a[d]+b[d]+bm[d], 0.f);
}

// score (4 einsums) -> masked softmax -> path rows (NPx3072)
__global__ __launch_bounds__(256) void k_scorepath(const float* __restrict__ qW,
                                                   const float* __restrict__ edge,
                                                   const int* __restrict__ hts,
                                                   const float* __restrict__ battp,
                                                   float* __restrict__ pathc)
{
    int g = blockIdx.x;
    int i = g / PP;
    int h = hts[2*g], t = hts[2*g+1];
    __shared__ float qs[4*DD];
    __shared__ float sc[EE];
    __shared__ float aw[EE];
    for (int d = threadIdx.x; d < 4*DD; d += 256) qs[d] = qW[(size_t)g*3072 + d];
    __syncthreads();
    const float* eb = edge + (size_t)i*EE*EE*DD;
    int lane = threadIdx.x & 63, wid = threadIdx.x >> 6;
    for (int v = wid; v < EE; v += 4) {
        const float* e1 = eb + (size_t)(h*EE+v)*DD;
        const float* e2 = eb + (size_t)(v*EE+t)*DD;
        const float* e3 = eb + (size_t)(t*EE+v)*DD;
        const float* e4 = eb + (size_t)(v*EE+h)*DD;
        float s = 0.f;
        for (int d = lane; d < DD; d += 64)
            s += qs[d]*e1[d] + qs[DD+d]*e2[d] + qs[2*DD+d]*e3[d] + qs[3*DD+d]*e4[d];
        #pragma unroll
        for (int o=32;o;o>>=1) s += __shfl_xor(s, o);
        if (lane==0) sc[v] = s + battp[0];
    }
    __syncthreads();
    if (threadIdx.x == 0) {
        float mx = -3.0e38f;
        for (int v=0;v<EE;++v){ float x = (v==h||v==t)? -1e30f : sc[v]; sc[v]=x; mx = fmaxf(mx,x); }
        float su=0.f;
        for (int v=0;v<EE;++v){ float e = expf(sc[v]-mx); aw[v]=e; su+=e; }
        float inv = 1.f/su;
        for (int v=0;v<EE;++v) aw[v]*=inv;
    }
    __syncthreads();
    for (int idx = threadIdx.x; idx < 4*DD; idx += 256) {
        int k = idx / DD, d = idx % DD;
        const float* e;
        int stride;
        if (k==0)      { e = eb + (size_t)h*EE*DD + d; stride = DD; }        // edge[h,v,d]
        else if (k==1) { e = eb + (size_t)t*DD + d;     stride = EE*DD; }    // edge[v,t,d]
        else if (k==2) { e = eb + (size_t)t*EE*DD + d;  stride = DD; }       // edge[t,v,d]
        else           { e = eb + (size_t)h*DD + d;     stride = EE*DD; }    // edge[v,h,d]
        float s = 0.f;
        #pragma unroll
        for (int v=0; v<EE; ++v) s += aw[v]*e[(size_t)v*stride];
        pathc[(size_t)g*3072 + idx] = s;
    }
}

// generic batched f32 GEMM: C1[,C2] = [relu](A@B [+ bias]); 64x64 tile, BK=16,
// 256 thr, 4x4/thread. LDS rows padded to 68 floats (272B = 17*16: float4-aligned,
// kills the 4-way bank conflict of the 64-stride A-scatter).
template<int RELU, int BIAS>
__global__ __launch_bounds__(256) void gemm_f32(const float* __restrict__ A, int lda, long long sA,
                                                const float* __restrict__ B, int ldb, long long sB,
                                                float* __restrict__ C1, float* __restrict__ C2,
                                                int ldc, long long sC,
                                                int M, int N, int K,
                                                const float* __restrict__ bias)
{
    int bz = blockIdx.z;
    A += (size_t)bz*sA;  B += (size_t)bz*sB;
    C1 += (size_t)bz*sC; if (C2) C2 += (size_t)bz*sC;
    __shared__ float As[16][68];
    __shared__ float Bs[16][68];
    int m0 = blockIdx.y*64, n0 = blockIdx.x*64;
    int t = threadIdx.x;
    int tx = t & 15, ty = t >> 4;
    int am = t >> 2;           // 0..63
    int ac = (t & 3) * 4;      // 0,4,8,12
    int bk = t >> 4;           // 0..15
    int bn = (t & 15) * 4;
    float acc[4][4] = {};
    for (int k0 = 0; k0 < K; k0 += 16) {
        float4 av = make_float4(0,0,0,0);
        int gm = m0 + am;
        if (gm < M) av = *reinterpret_cast<const float4*>(A + (size_t)gm*lda + k0 + ac);
        As[ac+0][am]=av.x; As[ac+1][am]=av.y; As[ac+2][am]=av.z; As[ac+3][am]=av.w;
        float4 bv = make_float4(0,0,0,0);
        int gn = n0 + bn;
        if (gn < N) bv = *reinterpret_cast<const float4*>(B + (size_t)(k0+bk)*ldb + gn);
        *reinterpret_cast<float4*>(&Bs[bk][bn]) = bv;
        __syncthreads();
        #pragma unroll
        for (int kk=0; kk<16; ++kk) {
            const float4 a = *reinterpret_cast<const float4*>(&As[kk][ty*4]);
            const float4 b = *reinterpret_cast<const float4*>(&Bs[kk][tx*4]);
            float ar[4] = {a.x,a.y,a.z,a.w};
            float br[4] = {b.x,b.y,b.z,b.w};
            #pragma unroll
            for (int r=0;r<4;++r)
                #pragma unroll
                for (int c2=0;c2<4;++c2) acc[r][c2] = fmaf(ar[r], br[c2], acc[r][c2]);
        }
        __syncthreads();
    }
    #pragma unroll
    for (int r=0;r<4;++r) {
        int gm = m0 + ty*4 + r;
        if (gm >= M) continue;
        #pragma unroll
        for (int c2=0;c2<4;++c2) {
            int gn = n0 + tx*4 + c2;
            if (gn >= N) continue;
            float v = acc[r][c2];
            if (BIAS) v += bias[gn];
            if (RELU) v = fmaxf(v, 0.f);
            C1[(size_t)gm*ldc + gn] = v;
            if (C2) C2[(size_t)gm*ldc + gn] = v;
        }
    }
}

// bilinear: out[m,l] = sum_{j,a,b} hs[m,ja]*ts[m,jb]*Wbil[jab,l]; K split into 48 slices
__global__ __launch_bounds__(256) void k_bil(const float* __restrict__ hsb,
                                             const float* __restrict__ tsb,
                                             const float* __restrict__ Wbil,
                                             float* __restrict__ partial)
{
    __shared__ float tsL[128][64];
    __shared__ float Bs[64*LOUT];
    int m0 = blockIdx.x * 128;
    int sl = blockIdx.y;               // 0..47
    int j = sl >> 2, quarter = sl & 3;
    int t = threadIdx.x;
    #pragma unroll
    for (int it=0; it<8; ++it) {
        int lin = t + it*256;
        int m = lin >> 4, q = (lin & 15) << 2;
        float4 v = make_float4(0,0,0,0);
        if (m0+m < NPAIR) v = *reinterpret_cast<const float4*>(tsb + (size_t)(m0+m)*DD + j*64 + q);
        *reinterpret_cast<float4*>(&tsL[m][q]) = v;
    }
    int tx = t & 15, ty = t >> 4;
    float acc[8][7];
    #pragma unroll
    for (int r=0;r<8;++r)
        #pragma unroll
        for (int s=0;s<7;++s) acc[r][s]=0.f;
    float ap[8];
    for (int c = 0; c < 16; ++c) {
        int a = quarter*16 + c;
        __syncthreads();
        size_t kb = ((size_t)j*4096 + (size_t)a*64)*LOUT;
        for (int idx = t; idx < 64*LOUT; idx += 256) Bs[idx] = Wbil[kb + idx];
        __syncthreads();
        #pragma unroll
        for (int r=0;r<8;++r) {
            int m = m0 + ty*8 + r;
            ap[r] = (m < NPAIR) ? hsb[(size_t)m*DD + j*64 + a] : 0.f;
        }
        for (int b=0;b<64;++b) {
            float pr[8];
            #pragma unroll
            for (int r=0;r<8;++r) pr[r] = ap[r]*tsL[ty*8+r][b];
            #pragma unroll
            for (int s=0;s<7;++s) {
                int l = tx + s*16;
                if (l < LOUT) {
                    float w = Bs[b*LOUT + l];
                    #pragma unroll
                    for (int r=0;r<8;++r) acc[r][s] = fmaf(pr[r], w, acc[r][s]);
                }
            }
        }
    }
    for (int r=0;r<8;++r) {
        int m = m0 + ty*8 + r;
        if (m >= NPAIR) continue;
        #pragma unroll
        for (int s=0;s<7;++s) {
            int l = tx + s*16;
            if (l < LOUT) partial[((size_t)sl*NPAIR + m)*LOUT + l] = acc[r][s];
        }
    }
}

__global__ __launch_bounds__(256) void k_bilred(const float* __restrict__ partial,
                                                const float* __restrict__ bbil,
                                                float* __restrict__ out)
{
    int idx = blockIdx.x*blockDim.x + threadIdx.x;
    if (idx >= NPAIR*LOUT) return;
    int l = idx % LOUT;
    float s = bbil[l];
    #pragma unroll 4
    for (int sl=0; sl<48; ++sl) s += partial[(size_t)sl*NPAIR*LOUT + idx];
    out[idx] = s;
}

extern "C" void kernel_launch(void* const* d_in, const int* in_sizes, int n_in,
                              void* d_out, int out_size, void* d_ws, size_t ws_size,
                              hipStream_t stream)
{
    (void)in_sizes; (void)n_in; (void)out_size;
    const float* seq   = (const float*)d_in[0];
    const float* att   = (const float*)d_in[1];
    const int*   ms    = (const int*)d_in[2];
    const int*   hts   = (const int*)d_in[3];
    const float* Wm1   = (const float*)d_in[4];
    const float* Wm2   = (const float*)d_in[5];
    const float* bm    = (const float*)d_in[6];
    const float* Watt  = (const float*)d_in[7];
    const float* batt  = (const float*)d_in[8];
    const float* Wpath = (const float*)d_in[9];
    const float* bpath = (const float*)d_in[10];
    const float* Whead = (const float*)d_in[11];
    const float* bhead = (const float*)d_in[12];
    const float* Wtail = (const float*)d_in[13];
    const float* btail = (const float*)d_in[14];
    const float* Wbil  = (const float*)d_in[15];
    const float* bbil  = (const float*)d_in[16];
    float* out = (float*)d_out;

    float* f = (float*)d_ws;
    float* eatt  = f;  f += (size_t)NDOC*EE*MM*CL;
    float* glob  = f;  f += (size_t)NDOC*EE*DD;
    float* qcat  = f;  f += (size_t)NPAIR*1536;
    float* hcat  = f;  f += (size_t)NPAIR*2304;
    float* tcat  = f;  f += (size_t)NPAIR*2304;
    float* pa    = f;  f += (size_t)NPAIR*CL;
    float* Abuf  = f;  f += (size_t)NDOC*EE*DD;
    float* Bbuf  = f;  f += (size_t)NDOC*EE*DD;
    float* edge  = f;  f += (size_t)NDOC*EE*EE*DD;
    float* qWb   = f;  f += (size_t)NPAIR*3072;
    float* pathc = f;  f += (size_t)NPAIR*3072;
    float* hsb   = f;  f += (size_t)NPAIR*DD;
    float* tsb   = f;  f += (size_t)NPAIR*DD;
    float* part  = f;  f += (size_t)48*NPAIR*LOUT;
    if ((size_t)((char*)f - (char*)d_ws) > ws_size) return;  // ws too small: fail loudly (out stays poisoned)

    k_prep<<<NDOC*EE*MM + NDOC*EE, 256, 0, stream>>>(att, seq, ms, eatt, glob);
    k_pairvec<<<NPAIR, 256, 0, stream>>>(seq, eatt, ms, hts, qcat, hcat, tcat, pa);

    // rs = pa @ seq_i  (batched over docs) -> written straight into hcat/tcat col block 1
    gemm_f32<0,0><<<dim3(DD/64, (PP+63)/64, NDOC), 256, 0, stream>>>(
        pa, CL, (long long)PP*CL, seq, DD, (long long)CL*DD,
        hcat + DD, tcat + DD, 2304, (long long)PP*2304,
        PP, DD, CL, nullptr);
    // A = glob @ Wm1 ; B = glob @ Wm2  (batched over docs)
    gemm_f32<0,0><<<dim3(DD/64, 1, NDOC), 256, 0, stream>>>(
        glob, DD, (long long)EE*DD, Wm1, DD, 0LL,
        Abuf, nullptr, DD, (long long)EE*DD, EE, DD, DD, nullptr);
    gemm_f32<0,0><<<dim3(DD/64, 1, NDOC), 256, 0, stream>>>(
        glob, DD, (long long)EE*DD, Wm2, DD, 0LL,
        Bbuf, nullptr, DD, (long long)EE*DD, EE, DD, DD, nullptr);
    k_edge<<<NDOC*EE*EE, 256, 0, stream>>>(Abuf, Bbuf, bm, edge);

    // qW = [new_hs|new_ts] @ Watt
    gemm_f32<0,0><<<dim3(3072/64, (NPAIR+63)/64, 1), 256, 0, stream>>>(
        qcat, 1536, 0LL, Watt, 3072, 0LL,
        qWb, nullptr, 3072, 0LL, NPAIR, 3072, 1536, nullptr);
    k_scorepath<<<NPAIR, 256, 0, stream>>>(qWb, edge, hts, batt, pathc);

    // path = relu(pathc @ Wpath + bpath) -> written straight into hcat/tcat col block 2
    gemm_f32<1,1><<<dim3(DD/64, (NPAIR+63)/64, 1), 256, 0, stream>>>(
        pathc, 3072, 0LL, Wpath, DD, 0LL,
        hcat + 2*DD, tcat + 2*DD, 2304, 0LL, NPAIR, DD, 3072, bpath);

    // hs = relu(hcat @ Whead + bhead) ; ts = relu(tcat @ Wtail + btail)
    gemm_f32<1,1><<<dim3(DD/64, (NPAIR+63)/64, 1), 256, 0, stream>>>(
        hcat, 2304, 0LL, Whead, DD, 0LL,
        hsb, nullptr, DD, 0LL, NPAIR, DD, 2304, bhead);
    gemm_f32<1,1><<<dim3(DD/64, (NPAIR+63)/64, 1), 256, 0, stream>>>(
        tcat, 2304, 0LL, Wtail, DD, 0LL,
        tsb, nullptr, DD, 0LL, NPAIR, DD, 2304, btail);

    // bilinear
    k_bil<<<dim3((NPAIR+127)/128, 48), 256, 0, stream>>>(hsb, tsb, Wbil, part);
    k_bilred<<<(NPAIR*LOUT+255)/256, 256, 0, stream>>>(part, bbil, out);
}

// Round 3
// 1061.438 us; speedup vs baseline: 1.5331x; 1.5331x over previous
//
#include <hip/hip_runtime.h>
#include <hip/hip_bf16.h>

#define NDOC 4
#define CL   512
#define DD   768
#define HH   12
#define EE   20
#define MM   4
#define PP   380
#define NPAIR 1520
#define LOUT 97

typedef unsigned short u16;
typedef short bf16x8 __attribute__((ext_vector_type(8)));
typedef u16   u16x8  __attribute__((ext_vector_type(8)));
typedef float f32x4  __attribute__((ext_vector_type(4)));

__device__ __forceinline__ u16 f2bf(float x){
    union { float f; unsigned u; } v; v.f = x;
    return (u16)((v.u + 0x7fffu + ((v.u >> 16) & 1u)) >> 16);
}
__device__ __forceinline__ float bf2f(u16 h){
    union { unsigned u; float f; } v; v.u = ((unsigned)h) << 16;
    return v.f;
}
__device__ __forceinline__ void splitf(float x, u16 &h, u16 &l){
    h = f2bf(x);
    l = f2bf(x - bf2f(h));
}

// ---------------------------------------------------------------------------
// Merged prep: blocks [0,320): eatt rows; [320,400): glob rows.
__global__ __launch_bounds__(256) void k_prep(const float* __restrict__ att,
                                              const float* __restrict__ seq,
                                              const int* __restrict__ ms,
                                              float* __restrict__ eatt,
                                              float* __restrict__ glob)
{
    int b = blockIdx.x;
    if (b < NDOC*EE*MM) {
        int row = b;
        int i = row / (EE*MM);
        int pos = ms[row] + 1;
        const float* base = att + ((size_t)i*HH)*CL*CL + (size_t)pos*CL;
        for (int c = threadIdx.x; c < CL; c += 256) {
            float s = 0.f;
            #pragma unroll
            for (int h = 0; h < HH; ++h) s += base[(size_t)h*CL*CL + c];
            eatt[(size_t)row*CL + c] = s * (1.0f/HH);
        }
    } else {
        int ie = b - NDOC*EE*MM;
        int i = ie / EE;
        const int* mp = ms + ie*MM;
        const float* sb = seq + (size_t)i*CL*DD;
        const float* r0 = sb + (size_t)(mp[0]+1)*DD;
        const float* r1 = sb + (size_t)(mp[1]+1)*DD;
        const float* r2 = sb + (size_t)(mp[2]+1)*DD;
        const float* r3 = sb + (size_t)(mp[3]+1)*DD;
        for (int d = threadIdx.x; d < DD; d += 256) {
            float a=r0[d], bb=r1[d], c=r2[d], e=r3[d];
            float mx = fmaxf(fmaxf(a,bb), fmaxf(c,e));
            float s = expf(a-mx)+expf(bb-mx)+expf(c-mx)+expf(e-mx);
            glob[(size_t)ie*DD + d] = mx + logf(s);
        }
    }
}

// Per pair: inline pair weights; new_hs/new_ts -> qcat(HL) & hcat/tcat(HL) col0; pa f32
__global__ __launch_bounds__(256) void k_pairvec(const float* __restrict__ seq,
                                                 const float* __restrict__ eatt,
                                                 const int* __restrict__ ms,
                                                 const int* __restrict__ hts,
                                                 u16* __restrict__ qcatH, u16* __restrict__ qcatL,
                                                 u16* __restrict__ hcatH, u16* __restrict__ hcatL,
                                                 u16* __restrict__ tcatH, u16* __restrict__ tcatL,
                                                 float* __restrict__ pa)
{
    int g = blockIdx.x;
    int i = g / PP;
    int h = hts[2*g], t = hts[2*g+1];
    const float* eh = eatt + (size_t)(i*EE+h)*MM*CL;
    const float* et = eatt + (size_t)(i*EE+t)*MM*CL;
    int ph[MM], pt[MM];
    #pragma unroll
    for (int m=0;m<MM;++m){ ph[m]=ms[(i*EE+h)*MM+m]+1; pt[m]=ms[(i*EE+t)*MM+m]+1; }
    float pH[MM], pT[MM]; float sh=0.f, st=0.f;
    #pragma unroll
    for (int m2=0; m2<MM; ++m2) {
        float s = 0.f, s2 = 0.f;
        #pragma unroll
        for (int m=0;m<MM;++m) { s += eh[m*CL + pt[m2]]; s2 += et[m*CL + ph[m2]]; }
        pH[m2] = s*0.25f;  sh += pH[m2];
        pT[m2] = s2*0.25f; st += pT[m2];
    }
    float rh = 1.f/(sh+1e-5f), rt = 1.f/(st+1e-5f);
    #pragma unroll
    for (int m=0;m<MM;++m){ pH[m]*=rh; pT[m]*=rt; }

    const float* sb = seq + (size_t)i*CL*DD;
    for (int d = threadIdx.x; d < DD; d += 256) {
        float nh = pT[0]*sb[(size_t)ph[0]*DD+d] + pT[1]*sb[(size_t)ph[1]*DD+d]
                 + pT[2]*sb[(size_t)ph[2]*DD+d] + pT[3]*sb[(size_t)ph[3]*DD+d];
        float nt = pH[0]*sb[(size_t)pt[0]*DD+d] + pH[1]*sb[(size_t)pt[1]*DD+d]
                 + pH[2]*sb[(size_t)pt[2]*DD+d] + pH[3]*sb[(size_t)pt[3]*DD+d];
        u16 hh,ll;
        splitf(nh,hh,ll);
        qcatH[(size_t)g*1536 + d]=hh;      qcatL[(size_t)g*1536 + d]=ll;
        hcatH[(size_t)g*2304 + d]=hh;      hcatL[(size_t)g*2304 + d]=ll;
        splitf(nt,hh,ll);
        qcatH[(size_t)g*1536 + DD + d]=hh; qcatL[(size_t)g*1536 + DD + d]=ll;
        tcatH[(size_t)g*2304 + d]=hh;      tcatL[(size_t)g*2304 + d]=ll;
    }
    float vv[2]; float lsum = 0.f;
    #pragma unroll
    for (int it=0; it<2; ++it) {
        int c = threadIdx.x + it*256;
        float na = pT[0]*eh[c] + pT[1]*eh[CL+c] + pT[2]*eh[2*CL+c] + pT[3]*eh[3*CL+c];
        float nb = pH[0]*et[c] + pH[1]*et[CL+c] + pH[2]*et[2*CL+c] + pH[3]*et[3*CL+c];
        vv[it] = na*nb; lsum += vv[it];
    }
    float tot = lsum;
    #pragma unroll
    for (int o=32;o;o>>=1) tot += __shfl_xor(tot, o);
    __shared__ float wsum[4];
    if ((threadIdx.x & 63)==0) wsum[threadIdx.x>>6] = tot;
    __syncthreads();
    float inv = 1.f/(wsum[0]+wsum[1]+wsum[2]+wsum[3] + 1e-5f);
    #pragma unroll
    for (int it=0; it<2; ++it)
        pa[(size_t)g*CL + threadIdx.x + it*256] = vv[it]*inv;
}

// edge[i,h,t,d] = relu(A[i,h,d] + B[i,t,d] + bm[d])
__global__ __launch_bounds__(256) void k_edge(const float* __restrict__ Ab,
                                              const float* __restrict__ Bb,
                                              const float* __restrict__ bm,
                                              float* __restrict__ edge)
{
    int iht = blockIdx.x;
    int i = iht/(EE*EE); int rem = iht%(EE*EE); int h = rem/EE; int tt = rem%EE;
    const float* a = Ab + (size_t)(i*EE+h)*DD;
    const float* b = Bb + (size_t)(i*EE+tt)*DD;
    float* e = edge + (size_t)iht*DD;
    for (int d=threadIdx.x; d<DD; d+=256)
        e[d] = fmaxf(a[d]+b[d]+bm[d], 0.f);
}

// score (4 einsums) -> masked softmax -> path rows (bf16 hi/lo out)
__global__ __launch_bounds__(256) void k_scorepath(const float* __restrict__ qW,
                                                   const float* __restrict__ edge,
                                                   const int* __restrict__ hts,
                                                   const float* __restrict__ battp,
                                                   u16* __restrict__ pathcH,
                                                   u16* __restrict__ pathcL)
{
    int g = blockIdx.x;
    int i = g / PP;
    int h = hts[2*g], t = hts[2*g+1];
    __shared__ float qs[4*DD];
    __shared__ float sc[EE];
    __shared__ float aw[EE];
    for (int d = threadIdx.x; d < 4*DD; d += 256) qs[d] = qW[(size_t)g*3072 + d];
    __syncthreads();
    const float* eb = edge + (size_t)i*EE*EE*DD;
    int lane = threadIdx.x & 63, wid = threadIdx.x >> 6;
    for (int v = wid; v < EE; v += 4) {
        const float* e1 = eb + (size_t)(h*EE+v)*DD;
        const float* e2 = eb + (size_t)(v*EE+t)*DD;
        const float* e3 = eb + (size_t)(t*EE+v)*DD;
        const float* e4 = eb + (size_t)(v*EE+h)*DD;
        float s = 0.f;
        for (int d = lane; d < DD; d += 64)
            s += qs[d]*e1[d] + qs[DD+d]*e2[d] + qs[2*DD+d]*e3[d] + qs[3*DD+d]*e4[d];
        #pragma unroll
        for (int o=32;o;o>>=1) s += __shfl_xor(s, o);
        if (lane==0) sc[v] = s + battp[0];
    }
    __syncthreads();
    if (threadIdx.x == 0) {
        float mx = -3.0e38f;
        for (int v=0;v<EE;++v){ float x = (v==h||v==t)? -1e30f : sc[v]; sc[v]=x; mx = fmaxf(mx,x); }
        float su=0.f;
        for (int v=0;v<EE;++v){ float e = expf(sc[v]-mx); aw[v]=e; su+=e; }
        float inv = 1.f/su;
        for (int v=0;v<EE;++v) aw[v]*=inv;
    }
    __syncthreads();
    for (int idx = threadIdx.x; idx < 4*DD; idx += 256) {
        int k = idx / DD, d = idx % DD;
        const float* e;
        int stride;
        if (k==0)      { e = eb + (size_t)h*EE*DD + d; stride = DD; }
        else if (k==1) { e = eb + (size_t)t*DD + d;     stride = EE*DD; }
        else if (k==2) { e = eb + (size_t)t*EE*DD + d;  stride = DD; }
        else           { e = eb + (size_t)h*DD + d;     stride = EE*DD; }
        float s = 0.f;
        #pragma unroll
        for (int v=0; v<EE; ++v) s += aw[v]*e[(size_t)v*stride];
        u16 hh,ll; splitf(s,hh,ll);
        pathcH[(size_t)g*3072 + idx] = hh;
        pathcL[(size_t)g*3072 + idx] = ll;
    }
}

// f32 vector GEMM (small ops: rs, Wm1/Wm2). 64x64 tile, BK=16.
template<int RELU, int BIAS, int BF16OUT>
__global__ __launch_bounds__(256) void gemm_f32(const float* __restrict__ A, int lda, long long sA,
                                                const float* __restrict__ B, int ldb, long long sB,
                                                float* __restrict__ C1,
                                                u16* __restrict__ C1H, u16* __restrict__ C1L,
                                                u16* __restrict__ C2H, u16* __restrict__ C2L,
                                                int ldc, long long sC,
                                                int M, int N, int K,
                                                const float* __restrict__ bias)
{
    int bz = blockIdx.z;
    A += (size_t)bz*sA;  B += (size_t)bz*sB;
    if (C1)  C1  += (size_t)bz*sC;
    if (BF16OUT) { C1H += (size_t)bz*sC; C1L += (size_t)bz*sC; C2H += (size_t)bz*sC; C2L += (size_t)bz*sC; }
    __shared__ float As[16][68];
    __shared__ float Bs[16][68];
    int m0 = blockIdx.y*64, n0 = blockIdx.x*64;
    int t = threadIdx.x;
    int tx = t & 15, ty = t >> 4;
    int am = t >> 2;
    int ac = (t & 3) * 4;
    int bk = t >> 4;
    int bn = (t & 15) * 4;
    float acc[4][4] = {};
    for (int k0 = 0; k0 < K; k0 += 16) {
        float4 av = make_float4(0,0,0,0);
        int gm = m0 + am;
        if (gm < M) av = *reinterpret_cast<const float4*>(A + (size_t)gm*lda + k0 + ac);
        As[ac+0][am]=av.x; As[ac+1][am]=av.y; As[ac+2][am]=av.z; As[ac+3][am]=av.w;
        float4 bv = make_float4(0,0,0,0);
        int gn = n0 + bn;
        if (gn < N) bv = *reinterpret_cast<const float4*>(B + (size_t)(k0+bk)*ldb + gn);
        *reinterpret_cast<float4*>(&Bs[bk][bn]) = bv;
        __syncthreads();
        #pragma unroll
        for (int kk=0; kk<16; ++kk) {
            const float4 a = *reinterpret_cast<const float4*>(&As[kk][ty*4]);
            const float4 b = *reinterpret_cast<const float4*>(&Bs[kk][tx*4]);
            float ar[4] = {a.x,a.y,a.z,a.w};
            float br[4] = {b.x,b.y,b.z,b.w};
            #pragma unroll
            for (int r=0;r<4;++r)
                #pragma unroll
                for (int c2=0;c2<4;++c2) acc[r][c2] = fmaf(ar[r], br[c2], acc[r][c2]);
        }
        __syncthreads();
    }
    #pragma unroll
    for (int r=0;r<4;++r) {
        int gm = m0 + ty*4 + r;
        if (gm >= M) continue;
        #pragma unroll
        for (int c2=0;c2<4;++c2) {
            int gn = n0 + tx*4 + c2;
            if (gn >= N) continue;
            float v = acc[r][c2];
            if (BIAS) v += bias[gn];
            if (RELU) v = fmaxf(v, 0.f);
            if (BF16OUT) {
                u16 hh,ll; splitf(v,hh,ll);
                C1H[(size_t)gm*ldc + gn] = hh;  C1L[(size_t)gm*ldc + gn] = ll;
                C2H[(size_t)gm*ldc + gn] = hh;  C2L[(size_t)gm*ldc + gn] = ll;
            } else {
                C1[(size_t)gm*ldc + gn] = v;
            }
        }
    }
}

// ---------------------------------------------------------------------------
// Split-bf16 MFMA GEMM. C = A@B^T-form: A [M][K] bf16 hi/lo, B from f32 [K][N]
// (transposed+split into LDS on the fly). 3 MFMAs per fragment pair:
// hi*hi + lo*hi + hi*lo  (error ~2^-16 rel, preserves f32-level accuracy).
// K-map for both A and B frags: k = 8*(lane>>4)+e  (consistent A/B permutation
// of the HW k order is contraction-invariant). C/D: row=(lane>>4)*4+reg,
// col=lane&15 (HW-verified m89).
#define BM_T 128
#define BK_T 32
#define KP   40      // padded LDS row (bf16 elems): 80B rows -> b128 reads ~2-way max

enum { MQW=0, MPATH=1, MHT=2, MBIL=3 };

template<int MODE, int BN>
__global__ __launch_bounds__(256) void gemm_mfma(
    const u16* __restrict__ AH, const u16* __restrict__ AL,
    const u16* __restrict__ A2H, const u16* __restrict__ A2L,
    const float* __restrict__ Bf, const float* __restrict__ B2f,
    const float* __restrict__ bias, const float* __restrict__ bias2,
    float* __restrict__ oF,
    u16* __restrict__ o1H, u16* __restrict__ o1L,
    u16* __restrict__ o2H, u16* __restrict__ o2L,
    int M, int N, int K, int ldb)
{
    __shared__ u16 AsH[BM_T*KP], AsL[BM_T*KP];
    __shared__ u16 BsH[BN*KP],  BsL[BN*KP];

    const u16 *aHp = AH, *aLp = AL;
    const float *Bp = Bf, *bp = bias;
    u16 *ouH = o1H, *ouL = o1L;
    if constexpr (MODE == MHT) {
        if (blockIdx.z == 1) { aHp=A2H; aLp=A2L; Bp=B2f; bp=bias2; ouH=o2H; ouL=o2L; }
    }

    const int t = threadIdx.x;
    const int m0 = blockIdx.y*BM_T;
    const int n0 = blockIdx.x*BN;

    constexpr int NWN = (BN==128)?2:1;
    constexpr int NWM = 4/NWN;
    constexpr int WM  = BM_T/NWM;
    constexpr int WN  = BN/NWN;
    constexpr int MFR = WM/16;
    constexpr int NFR = WN/16;
    constexpr int EPT = BN/8;       // B elems per thread per stage

    const int lane = t & 63, wid = t >> 6;
    const int wr = wid / NWN, wc = wid % NWN;
    const int lrow = lane & 15, lg = lane >> 4;

    f32x4 acc[MFR][NFR];
    #pragma unroll
    for (int i=0;i<MFR;++i)
        #pragma unroll
        for (int j=0;j<NFR;++j) acc[i][j] = f32x4{0.f,0.f,0.f,0.f};

    const int kbase  = (MODE==MBIL) ? blockIdx.z*(49152/16) : 0;
    const int ktiles = ((MODE==MBIL) ? (49152/16) : K) / BK_T;

    const int arow = t>>1, ahalf = t&1;
    const int bkk = t>>3, bc = t&7;

    for (int kt = 0; kt < ktiles; ++kt) {
        const int k0 = kbase + kt*BK_T;
        // ---- stage A (128 x 32 bf16 hi/lo) ----
        {
            u16 hv[16], lv[16];
            int gm = m0 + arow;
            bool ok = (gm < M);
            if constexpr (MODE != MBIL) {
                if (ok) {
                    const u16* phh = aHp + (size_t)gm*K + k0 + ahalf*16;
                    const u16* pll = aLp + (size_t)gm*K + k0 + ahalf*16;
                    *(u16x8*)&hv[0] = *(const u16x8*)phh;
                    *(u16x8*)&hv[8] = *(const u16x8*)(phh+8);
                    *(u16x8*)&lv[0] = *(const u16x8*)pll;
                    *(u16x8*)&lv[8] = *(const u16x8*)(pll+8);
                }
            } else {
                if (ok) {
                    int j = k0 >> 12, a = (k0 >> 6) & 63;
                    int bst = (k0 & 63) + ahalf*16;
                    size_t hsi = (size_t)gm*768 + j*64 + a;
                    float hsv = bf2f(AH[hsi]) + bf2f(AL[hsi]);
                    const u16* tph = A2H + (size_t)gm*768 + j*64 + bst;
                    const u16* tpl = A2L + (size_t)gm*768 + j*64 + bst;
                    u16 th[16], tl[16];
                    *(u16x8*)&th[0] = *(const u16x8*)tph;  *(u16x8*)&th[8] = *(const u16x8*)(tph+8);
                    *(u16x8*)&tl[0] = *(const u16x8*)tpl;  *(u16x8*)&tl[8] = *(const u16x8*)(tpl+8);
                    #pragma unroll
                    for (int i2=0;i2<16;++i2){
                        float p = hsv * (bf2f(th[i2]) + bf2f(tl[i2]));
                        splitf(p, hv[i2], lv[i2]);
                    }
                }
            }
            if (!ok) { for (int i2=0;i2<16;++i2){ hv[i2]=0; lv[i2]=0; } }
            *(u16x8*)&AsH[arow*KP + ahalf*16]     = *(u16x8*)&hv[0];
            *(u16x8*)&AsH[arow*KP + ahalf*16 + 8] = *(u16x8*)&hv[8];
            *(u16x8*)&AsL[arow*KP + ahalf*16]     = *(u16x8*)&lv[0];
            *(u16x8*)&AsL[arow*KP + ahalf*16 + 8] = *(u16x8*)&lv[8];
        }
        // ---- stage B: transpose + split from f32 [K][N] ----
        {
            const float* src = Bp + (size_t)(k0 + bkk)*ldb + n0 + bc*EPT;
            float vals[EPT];
            if constexpr (MODE == MBIL) {
                #pragma unroll
                for (int i2=0;i2<EPT;++i2){
                    int gn = n0 + bc*EPT + i2;
                    vals[i2] = (gn < N) ? src[i2] : 0.f;
                }
            } else {
                #pragma unroll
                for (int i2=0;i2<EPT;i2+=4)
                    *reinterpret_cast<float4*>(&vals[i2]) = *reinterpret_cast<const float4*>(src+i2);
            }
            #pragma unroll
            for (int i2=0;i2<EPT;++i2){
                u16 hh,ll; splitf(vals[i2],hh,ll);
                BsH[(bc*EPT+i2)*KP + bkk] = hh;
                BsL[(bc*EPT+i2)*KP + bkk] = ll;
            }
        }
        __syncthreads();
        // ---- MFMA ----
        {
            bf16x8 ah[MFR], al[MFR], bh[NFR], bl[NFR];
            #pragma unroll
            for (int mi=0;mi<MFR;++mi){
                int off = (wr*WM + mi*16 + lrow)*KP + lg*8;
                ah[mi] = *(const bf16x8*)&AsH[off];
                al[mi] = *(const bf16x8*)&AsL[off];
            }
            #pragma unroll
            for (int ni=0;ni<NFR;++ni){
                int off = (wc*WN + ni*16 + lrow)*KP + lg*8;
                bh[ni] = *(const bf16x8*)&BsH[off];
                bl[ni] = *(const bf16x8*)&BsL[off];
            }
            #pragma unroll
            for (int mi=0;mi<MFR;++mi)
                #pragma unroll
                for (int ni=0;ni<NFR;++ni){
                    acc[mi][ni] = __builtin_amdgcn_mfma_f32_16x16x32_bf16(ah[mi], bh[ni], acc[mi][ni], 0,0,0);
                    acc[mi][ni] = __builtin_amdgcn_mfma_f32_16x16x32_bf16(al[mi], bh[ni], acc[mi][ni], 0,0,0);
                    acc[mi][ni] = __builtin_amdgcn_mfma_f32_16x16x32_bf16(ah[mi], bl[ni], acc[mi][ni], 0,0,0);
                }
        }
        __syncthreads();
    }
    // ---- epilogue ----
    #pragma unroll
    for (int mi=0;mi<MFR;++mi)
        #pragma unroll
        for (int ni=0;ni<NFR;++ni)
            #pragma unroll
            for (int r=0;r<4;++r){
                int gm = m0 + wr*WM + mi*16 + lg*4 + r;
                int gn = n0 + wc*WN + ni*16 + lrow;
                if (gm >= M) continue;
                float v = acc[mi][ni][r];
                if constexpr (MODE==MQW) {
                    oF[(size_t)gm*N + gn] = v;
                } else if constexpr (MODE==MPATH) {
                    v = fmaxf(v + bp[gn], 0.f);
                    u16 hh,ll; splitf(v,hh,ll);
                    o1H[(size_t)gm*2304+gn]=hh; o1L[(size_t)gm*2304+gn]=ll;
                    o2H[(size_t)gm*2304+gn]=hh; o2L[(size_t)gm*2304+gn]=ll;
                } else if constexpr (MODE==MHT) {
                    v = fmaxf(v + bp[gn], 0.f);
                    u16 hh,ll; splitf(v,hh,ll);
                    ouH[(size_t)gm*768+gn]=hh; ouL[(size_t)gm*768+gn]=ll;
                } else {
                    if (gn < N) oF[((size_t)blockIdx.z*NPAIR + gm)*LOUT + gn] = v;
                }
            }
}

__global__ __launch_bounds__(256) void k_bilred(const float* __restrict__ partial,
                                                const float* __restrict__ bbil,
                                                float* __restrict__ out)
{
    int idx = blockIdx.x*blockDim.x + threadIdx.x;
    if (idx >= NPAIR*LOUT) return;
    int l = idx % LOUT;
    float s = bbil[l];
    #pragma unroll 4
    for (int sl=0; sl<16; ++sl) s += partial[(size_t)sl*NPAIR*LOUT + idx];
    out[idx] = s;
}

extern "C" void kernel_launch(void* const* d_in, const int* in_sizes, int n_in,
                              void* d_out, int out_size, void* d_ws, size_t ws_size,
                              hipStream_t stream)
{
    (void)in_sizes; (void)n_in; (void)out_size;
    const float* seq   = (const float*)d_in[0];
    const float* att   = (const float*)d_in[1];
    const int*   ms    = (const int*)d_in[2];
    const int*   hts   = (const int*)d_in[3];
    const float* Wm1   = (const float*)d_in[4];
    const float* Wm2   = (const float*)d_in[5];
    const float* bm    = (const float*)d_in[6];
    const float* Watt  = (const float*)d_in[7];
    const float* batt  = (const float*)d_in[8];
    const float* Wpath = (const float*)d_in[9];
    const float* bpath = (const float*)d_in[10];
    const float* Whead = (const float*)d_in[11];
    const float* bhead = (const float*)d_in[12];
    const float* Wtail = (const float*)d_in[13];
    const float* btail = (const float*)d_in[14];
    const float* Wbil  = (const float*)d_in[15];
    const float* bbil  = (const float*)d_in[16];
    float* out = (float*)d_out;

    char* p = (char*)d_ws;
    auto alloc = [&](size_t bytes)->char* {
        char* r = p; p += (bytes + 255) & ~(size_t)255; return r;
    };
    float* eatt   = (float*)alloc((size_t)NDOC*EE*MM*CL*4);
    float* glob   = (float*)alloc((size_t)NDOC*EE*DD*4);
    float* pa     = (float*)alloc((size_t)NPAIR*CL*4);
    float* Abuf   = (float*)alloc((size_t)NDOC*EE*DD*4);
    float* Bbuf   = (float*)alloc((size_t)NDOC*EE*DD*4);
    float* edge   = (float*)alloc((size_t)NDOC*EE*EE*DD*4);
    float* qWb    = (float*)alloc((size_t)NPAIR*3072*4);
    float* part   = (float*)alloc((size_t)16*NPAIR*LOUT*4);
    u16* qcatH  = (u16*)alloc((size_t)NPAIR*1536*2);
    u16* qcatL  = (u16*)alloc((size_t)NPAIR*1536*2);
    u16* hcatH  = (u16*)alloc((size_t)NPAIR*2304*2);
    u16* hcatL  = (u16*)alloc((size_t)NPAIR*2304*2);
    u16* tcatH  = (u16*)alloc((size_t)NPAIR*2304*2);
    u16* tcatL  = (u16*)alloc((size_t)NPAIR*2304*2);
    u16* pathcH = (u16*)alloc((size_t)NPAIR*3072*2);
    u16* pathcL = (u16*)alloc((size_t)NPAIR*3072*2);
    u16* hsH    = (u16*)alloc((size_t)NPAIR*DD*2);
    u16* hsL    = (u16*)alloc((size_t)NPAIR*DD*2);
    u16* tsH    = (u16*)alloc((size_t)NPAIR*DD*2);
    u16* tsL    = (u16*)alloc((size_t)NPAIR*DD*2);
    if ((size_t)(p - (char*)d_ws) > ws_size) return;  // fail loudly (out stays poisoned)

    k_prep<<<NDOC*EE*MM + NDOC*EE, 256, 0, stream>>>(att, seq, ms, eatt, glob);
    k_pairvec<<<NPAIR, 256, 0, stream>>>(seq, eatt, ms, hts,
                                         qcatH, qcatL, hcatH, hcatL, tcatH, tcatL, pa);

    // rs = pa @ seq_i  (f32 vector GEMM, batched) -> hcat/tcat col block 1 (bf16 hi/lo)
    gemm_f32<0,0,1><<<dim3(DD/64, (PP+63)/64, NDOC), 256, 0, stream>>>(
        pa, CL, (long long)PP*CL, seq, DD, (long long)CL*DD,
        nullptr, hcatH + DD, hcatL + DD, tcatH + DD, tcatL + DD,
        2304, (long long)PP*2304, PP, DD, CL, nullptr);
    // A = glob @ Wm1 ; B = glob @ Wm2  (f32)
    gemm_f32<0,0,0><<<dim3(DD/64, 1, NDOC), 256, 0, stream>>>(
        glob, DD, (long long)EE*DD, Wm1, DD, 0LL,
        Abuf, nullptr,nullptr,nullptr,nullptr, DD, (long long)EE*DD, EE, DD, DD, nullptr);
    gemm_f32<0,0,0><<<dim3(DD/64, 1, NDOC), 256, 0, stream>>>(
        glob, DD, (long long)EE*DD, Wm2, DD, 0LL,
        Bbuf, nullptr,nullptr,nullptr,nullptr, DD, (long long)EE*DD, EE, DD, DD, nullptr);
    k_edge<<<NDOC*EE*EE, 256, 0, stream>>>(Abuf, Bbuf, bm, edge);

    // qW = qcat @ Watt   (split-bf16 MFMA)
    gemm_mfma<MQW,128><<<dim3(3072/128, (NPAIR+127)/128, 1), 256, 0, stream>>>(
        qcatH, qcatL, nullptr, nullptr, Watt, nullptr, nullptr, nullptr,
        qWb, nullptr,nullptr,nullptr,nullptr, NPAIR, 3072, 1536, 3072);
    k_scorepath<<<NPAIR, 256, 0, stream>>>(qWb, edge, hts, batt, pathcH, pathcL);

    // path = relu(pathc @ Wpath + bpath) -> hcat/tcat col block 2 (bf16 hi/lo)
    gemm_mfma<MPATH,64><<<dim3(768/64, (NPAIR+127)/128, 1), 256, 0, stream>>>(
        pathcH, pathcL, nullptr, nullptr, Wpath, nullptr, bpath, nullptr,
        nullptr, hcatH + 2*DD, hcatL + 2*DD, tcatH + 2*DD, tcatL + 2*DD,
        NPAIR, 768, 3072, 768);

    // hs = relu(hcat@Whead+bhead) ; ts = relu(tcat@Wtail+btail)   (z-batched)
    gemm_mfma<MHT,64><<<dim3(768/64, (NPAIR+127)/128, 2), 256, 0, stream>>>(
        hcatH, hcatL, tcatH, tcatL, Whead, Wtail, bhead, btail,
        nullptr, hsH, hsL, tsH, tsL, NPAIR, 768, 2304, 768);

    // bilinear: A-tile built on the fly from hs/ts; K split x16 across blocks
    gemm_mfma<MBIL,64><<<dim3(2, (NPAIR+127)/128, 16), 256, 0, stream>>>(
        hsH, hsL, tsH, tsL, Wbil, nullptr, nullptr, nullptr,
        part, nullptr,nullptr,nullptr,nullptr, NPAIR, LOUT, 49152, LOUT);

    k_bilred<<<(NPAIR*LOUT+255)/256, 256, 0, stream>>>(part, bbil, out);
}

// Round 5
// 775.551 us; speedup vs baseline: 2.0983x; 1.3686x over previous
//
#include <hip/hip_runtime.h>
#include <hip/hip_bf16.h>

#define NDOC 4
#define CL   512
#define DD   768
#define HH   12
#define EE   20
#define MM   4
#define PP   380
#define NPAIR 1520
#define LOUT 97
#define KP   40   // padded LDS row length in u16 (80 B)

typedef unsigned short u16;
typedef short bf16x8 __attribute__((ext_vector_type(8)));
typedef u16   u16x8  __attribute__((ext_vector_type(8)));
typedef u16   u16x4  __attribute__((ext_vector_type(4)));
typedef float f32x4  __attribute__((ext_vector_type(4)));

#define Z8 (u16x8){0,0,0,0,0,0,0,0}

__device__ __forceinline__ u16 f2bf(float x){
    union { float f; unsigned u; } v; v.f = x;
    return (u16)((v.u + 0x7fffu + ((v.u >> 16) & 1u)) >> 16);
}
__device__ __forceinline__ float bf2f(u16 h){
    union { unsigned u; float f; } v; v.u = ((unsigned)h) << 16;
    return v.f;
}
// RNE split (data feeding further GEMMs / stored weights)
__device__ __forceinline__ void splitf(float x, u16 &h, u16 &l){
    h = f2bf(x);
    l = f2bf(x - bf2f(h));
}
// cheap truncation split (MBIL product tiles): err ~2^-15 rel, corrected by lo-term MFMA
__device__ __forceinline__ void splitf_trunc(float x, u16 &h, u16 &l){
    union { float f; unsigned u; } v; v.f = x;
    h = (u16)(v.u >> 16);
    union { unsigned u; float f; } w; w.u = v.u & 0xffff0000u;
    union { float f; unsigned u; } s; s.f = x - w.f;   // exact
    l = (u16)(s.u >> 16);
}

// ---------------------------------------------------------------------------
// transpose + split: W [K][N] f32 -> WH/WL [Npad][K] u16 (rows >= N zero-filled)
// K, Npad multiples of 64. grid (Npad/64, K/64, batch)
__global__ __launch_bounds__(256) void k_wsplit(const float* __restrict__ W,
                                                u16* __restrict__ WH, u16* __restrict__ WL,
                                                int K, int N, long long srcStride,
                                                long long dstStride)
{
    __shared__ u16 tH[64][66], tL[64][66];
    const float* Wp = W + (size_t)blockIdx.z*srcStride;
    u16* WHp = WH + (size_t)blockIdx.z*dstStride;
    u16* WLp = WL + (size_t)blockIdx.z*dstStride;
    int n0 = blockIdx.x*64, k0 = blockIdx.y*64;
    int t = threadIdx.x;
    int kr = t>>4, c4 = (t&15)*4;
    bool vec4 = ((N & 3) == 0);
    #pragma unroll
    for (int rr=0; rr<4; ++rr) {
        int k = k0 + kr + rr*16;
        float arr[4];
        if (vec4 && n0 + c4 + 3 < N) {
            float4 v = *(const float4*)(Wp + (size_t)k*N + n0 + c4);
            arr[0]=v.x; arr[1]=v.y; arr[2]=v.z; arr[3]=v.w;
        } else {
            #pragma unroll
            for (int i=0;i<4;++i){ int n=n0+c4+i; arr[i] = (n<N)? Wp[(size_t)k*N+n] : 0.f; }
        }
        #pragma unroll
        for (int i=0;i<4;++i){
            u16 hh,ll; splitf(arr[i],hh,ll);
            tH[c4+i][kr+rr*16] = hh;
            tL[c4+i][kr+rr*16] = ll;
        }
    }
    __syncthreads();
    int nr = t>>4, kc = (t&15)*4;
    #pragma unroll
    for (int rr=0; rr<4; ++rr) {
        int nl = nr + rr*16;
        u16x4 vh, vl;
        #pragma unroll
        for (int i=0;i<4;++i){ vh[i]=tH[nl][kc+i]; vl[i]=tL[nl][kc+i]; }
        size_t o = (size_t)(n0+nl)*K + k0 + kc;
        *(u16x4*)(WHp + o) = vh;
        *(u16x4*)(WLp + o) = vl;
    }
}

// ---------------------------------------------------------------------------
// prep: blocks [0,320): eatt rows; [320,400): glob rows
__global__ __launch_bounds__(256) void k_prep(const float* __restrict__ att,
                                              const float* __restrict__ seq,
                                              const int* __restrict__ ms,
                                              float* __restrict__ eatt,
                                              float* __restrict__ glob)
{
    int b = blockIdx.x;
    if (b < NDOC*EE*MM) {
        int row = b;
        int i = row / (EE*MM);
        int pos = ms[row] + 1;
        const float* base = att + ((size_t)i*HH)*CL*CL + (size_t)pos*CL;
        for (int c = threadIdx.x; c < CL; c += 256) {
            float s = 0.f;
            #pragma unroll
            for (int h = 0; h < HH; ++h) s += base[(size_t)h*CL*CL + c];
            eatt[(size_t)row*CL + c] = s * (1.0f/HH);
        }
    } else {
        int ie = b - NDOC*EE*MM;
        int i = ie / EE;
        const int* mp = ms + ie*MM;
        const float* sb = seq + (size_t)i*CL*DD;
        const float* r0 = sb + (size_t)(mp[0]+1)*DD;
        const float* r1 = sb + (size_t)(mp[1]+1)*DD;
        const float* r2 = sb + (size_t)(mp[2]+1)*DD;
        const float* r3 = sb + (size_t)(mp[3]+1)*DD;
        for (int d = threadIdx.x; d < DD; d += 256) {
            float a=r0[d], bb=r1[d], c=r2[d], e=r3[d];
            float mx = fmaxf(fmaxf(a,bb), fmaxf(c,e));
            float s = expf(a-mx)+expf(bb-mx)+expf(c-mx)+expf(e-mx);
            glob[(size_t)ie*DD + d] = mx + logf(s);
        }
    }
}

// per pair: pair weights inline; nh/nt (bf16 hi/lo), pa (bf16 hi/lo)
__global__ __launch_bounds__(256) void k_pairvec(const float* __restrict__ seq,
                                                 const float* __restrict__ eatt,
                                                 const int* __restrict__ ms,
                                                 const int* __restrict__ hts,
                                                 u16* __restrict__ nhH, u16* __restrict__ nhL,
                                                 u16* __restrict__ ntH, u16* __restrict__ ntL,
                                                 u16* __restrict__ paH, u16* __restrict__ paL)
{
    int g = blockIdx.x;
    int i = g / PP;
    int h = hts[2*g], t = hts[2*g+1];
    const float* eh = eatt + (size_t)(i*EE+h)*MM*CL;
    const float* et = eatt + (size_t)(i*EE+t)*MM*CL;
    int ph[MM], pt[MM];
    #pragma unroll
    for (int m=0;m<MM;++m){ ph[m]=ms[(i*EE+h)*MM+m]+1; pt[m]=ms[(i*EE+t)*MM+m]+1; }
    float pH[MM], pT[MM]; float sh=0.f, st=0.f;
    #pragma unroll
    for (int m2=0; m2<MM; ++m2) {
        float s = 0.f, s2 = 0.f;
        #pragma unroll
        for (int m=0;m<MM;++m) { s += eh[m*CL + pt[m2]]; s2 += et[m*CL + ph[m2]]; }
        pH[m2] = s*0.25f;  sh += pH[m2];
        pT[m2] = s2*0.25f; st += pT[m2];
    }
    float rh = 1.f/(sh+1e-5f), rt = 1.f/(st+1e-5f);
    #pragma unroll
    for (int m=0;m<MM;++m){ pH[m]*=rh; pT[m]*=rt; }

    const float* sb = seq + (size_t)i*CL*DD;
    for (int d = threadIdx.x; d < DD; d += 256) {
        float nh = pT[0]*sb[(size_t)ph[0]*DD+d] + pT[1]*sb[(size_t)ph[1]*DD+d]
                 + pT[2]*sb[(size_t)ph[2]*DD+d] + pT[3]*sb[(size_t)ph[3]*DD+d];
        float nt = pH[0]*sb[(size_t)pt[0]*DD+d] + pH[1]*sb[(size_t)pt[1]*DD+d]
                 + pH[2]*sb[(size_t)pt[2]*DD+d] + pH[3]*sb[(size_t)pt[3]*DD+d];
        u16 hh,ll;
        splitf(nh,hh,ll);
        nhH[(size_t)g*DD + d]=hh; nhL[(size_t)g*DD + d]=ll;
        splitf(nt,hh,ll);
        ntH[(size_t)g*DD + d]=hh; ntL[(size_t)g*DD + d]=ll;
    }
    float vv[2]; float lsum = 0.f;
    #pragma unroll
    for (int it=0; it<2; ++it) {
        int c = threadIdx.x + it*256;
        float na = pT[0]*eh[c] + pT[1]*eh[CL+c] + pT[2]*eh[2*CL+c] + pT[3]*eh[3*CL+c];
        float nb = pH[0]*et[c] + pH[1]*et[CL+c] + pH[2]*et[2*CL+c] + pH[3]*et[3*CL+c];
        vv[it] = na*nb; lsum += vv[it];
    }
    float tot = lsum;
    #pragma unroll
    for (int o=32;o;o>>=1) tot += __shfl_xor(tot, o);
    __shared__ float wsum[4];
    if ((threadIdx.x & 63)==0) wsum[threadIdx.x>>6] = tot;
    __syncthreads();
    float inv = 1.f/(wsum[0]+wsum[1]+wsum[2]+wsum[3] + 1e-5f);
    #pragma unroll
    for (int it=0; it<2; ++it){
        int c = threadIdx.x + it*256;
        u16 hh,ll; splitf(vv[it]*inv,hh,ll);
        paH[(size_t)g*CL + c]=hh; paL[(size_t)g*CL + c]=ll;
    }
}

// edge = relu(A[h] + B[t] + bm)
__global__ __launch_bounds__(256) void k_edge(const float* __restrict__ Ab,
                                              const float* __restrict__ Bb,
                                              const float* __restrict__ bm,
                                              float* __restrict__ edge)
{
    int iht = blockIdx.x;
    int i = iht/(EE*EE); int rem = iht%(EE*EE); int h = rem/EE; int tt = rem%EE;
    const float* a = Ab + (size_t)(i*EE+h)*DD;
    const float* b = Bb + (size_t)(i*EE+tt)*DD;
    float* e = edge + (size_t)iht*DD;
    for (int d=threadIdx.x; d<DD; d+=256)
        e[d] = fmaxf(a[d]+b[d]+bm[d], 0.f);
}

// score (4 einsums) -> masked softmax -> path rows (bf16 hi/lo)
__global__ __launch_bounds__(256) void k_scorepath(const float* __restrict__ qW,
                                                   const float* __restrict__ edge,
                                                   const int* __restrict__ hts,
                                                   const float* __restrict__ battp,
                                                   u16* __restrict__ pathcH,
                                                   u16* __restrict__ pathcL)
{
    int g = blockIdx.x;
    int i = g / PP;
    int h = hts[2*g], t = hts[2*g+1];
    __shared__ float qs[4*DD];
    __shared__ float sc[EE];
    __shared__ float aw[EE];
    for (int d4 = threadIdx.x; d4 < DD; d4 += 256)
        *(float4*)&qs[d4*4] = *(const float4*)(qW + (size_t)g*3072 + d4*4);
    __syncthreads();
    const float* eb = edge + (size_t)i*EE*EE*DD;
    int lane = threadIdx.x & 63, wid = threadIdx.x >> 6;
    for (int v = wid; v < EE; v += 4) {
        const float* e1 = eb + (size_t)(h*EE+v)*DD;
        const float* e2 = eb + (size_t)(v*EE+t)*DD;
        const float* e3 = eb + (size_t)(t*EE+v)*DD;
        const float* e4 = eb + (size_t)(v*EE+h)*DD;
        float s = 0.f;
        for (int d = lane; d < DD; d += 64)
            s += qs[d]*e1[d] + qs[DD+d]*e2[d] + qs[2*DD+d]*e3[d] + qs[3*DD+d]*e4[d];
        #pragma unroll
        for (int o=32;o;o>>=1) s += __shfl_xor(s, o);
        if (lane==0) sc[v] = s + battp[0];
    }
    __syncthreads();
    if (threadIdx.x == 0) {
        float mx = -3.0e38f;
        for (int v=0;v<EE;++v){ float x = (v==h||v==t)? -1e30f : sc[v]; sc[v]=x; mx = fmaxf(mx,x); }
        float su=0.f;
        for (int v=0;v<EE;++v){ float e = expf(sc[v]-mx); aw[v]=e; su+=e; }
        float inv = 1.f/su;
        for (int v=0;v<EE;++v) aw[v]*=inv;
    }
    __syncthreads();
    for (int idx = threadIdx.x; idx < 4*DD; idx += 256) {
        int k = idx / DD, d = idx % DD;
        const float* e;
        int stride;
        if (k==0)      { e = eb + (size_t)h*EE*DD + d; stride = DD; }
        else if (k==1) { e = eb + (size_t)t*DD + d;     stride = EE*DD; }
        else if (k==2) { e = eb + (size_t)t*EE*DD + d;  stride = DD; }
        else           { e = eb + (size_t)h*DD + d;     stride = EE*DD; }
        float s = 0.f;
        #pragma unroll
        for (int v=0; v<EE; ++v) s += aw[v]*e[(size_t)v*stride];
        u16 hh,ll; splitf(s,hh,ll);
        pathcH[(size_t)g*3072 + idx] = hh;
        pathcL[(size_t)g*3072 + idx] = ll;
    }
}

// small f32 GEMM (glob @ Wm1/Wm2, M=20/doc)
__global__ __launch_bounds__(256) void gemm_f32s(const float* __restrict__ A, int lda, long long sA,
                                                 const float* __restrict__ B, int ldb,
                                                 float* __restrict__ C, int ldc, long long sC,
                                                 int M, int N, int K)
{
    int bz = blockIdx.z;
    A += (size_t)bz*sA;  C += (size_t)bz*sC;
    __shared__ float As[16][68];
    __shared__ float Bs[16][68];
    int m0 = blockIdx.y*64, n0 = blockIdx.x*64;
    int t = threadIdx.x;
    int tx = t & 15, ty = t >> 4;
    int am = t >> 2, ac = (t & 3) * 4;
    int bk = t >> 4, bn = (t & 15) * 4;
    float acc[4][4] = {};
    for (int k0 = 0; k0 < K; k0 += 16) {
        float4 av = make_float4(0,0,0,0);
        int gm = m0 + am;
        if (gm < M) av = *reinterpret_cast<const float4*>(A + (size_t)gm*lda + k0 + ac);
        As[ac+0][am]=av.x; As[ac+1][am]=av.y; As[ac+2][am]=av.z; As[ac+3][am]=av.w;
        float4 bv = *reinterpret_cast<const float4*>(B + (size_t)(k0+bk)*ldb + n0 + bn);
        *reinterpret_cast<float4*>(&Bs[bk][bn]) = bv;
        __syncthreads();
        #pragma unroll
        for (int kk=0; kk<16; ++kk) {
            const float4 a = *reinterpret_cast<const float4*>(&As[kk][ty*4]);
            const float4 b = *reinterpret_cast<const float4*>(&Bs[kk][tx*4]);
            float ar[4] = {a.x,a.y,a.z,a.w};
            float br[4] = {b.x,b.y,b.z,b.w};
            #pragma unroll
            for (int r=0;r<4;++r)
                #pragma unroll
                for (int c2=0;c2<4;++c2) acc[r][c2] = fmaf(ar[r], br[c2], acc[r][c2]);
        }
        __syncthreads();
    }
    #pragma unroll
    for (int r=0;r<4;++r) {
        int gm = m0 + ty*4 + r;
        if (gm >= M) continue;
        #pragma unroll
        for (int c2=0;c2<4;++c2)
            C[(size_t)gm*ldc + n0 + tx*4 + c2] = acc[r][c2];
    }
}

// ---------------------------------------------------------------------------
// Split-bf16 MFMA GEMM. A: segmented [M][segsz] bf16 hi/lo buffers (or MBIL
// product built on the fly). B: pre-split pre-transposed [N][Ktot] bf16 hi/lo.
// 3 MFMAs per fragment pair: hi*hi + lo*hi + hi*lo.
enum { MQW=0, MSPLIT=1, MRS=2, MBIL=3 };

template<int MODE, int BM, int BN>
__global__ __launch_bounds__(256) void gemm_mfma(
    const u16* __restrict__ aH0, const u16* __restrict__ aL0,
    const u16* __restrict__ aH1, const u16* __restrict__ aL1,
    const u16* __restrict__ aH2, const u16* __restrict__ aL2,
    const u16* __restrict__ bH, const u16* __restrict__ bL,
    const float* __restrict__ bias,
    float* __restrict__ oF,
    u16* __restrict__ oH, u16* __restrict__ oL,
    int M, int N, int Ktot, int segsz)
{
    constexpr int NWN = BN/64;
    constexpr int NWM = 4/NWN;
    constexpr int WM  = BM/NWM;
    constexpr int MFR = WM/16;
    constexpr int NFR = 4;
    __shared__ u16 AsH[BM*KP], AsL[BM*KP], BsH[BN*KP], BsL[BN*KP];

    const int t = threadIdx.x;
    const int z = blockIdx.z;
    const int m0 = blockIdx.y*BM, n0 = blockIdx.x*BN;
    const int lane = t & 63, wid = t >> 6;
    const int wr = wid / NWN, wc = wid % NWN;
    const int lrow = lane & 15, lg = lane >> 4;

    const u16 *segH0=aH0, *segL0=aL0;
    const u16 *bHp = bH, *bLp = bL;
    int Mloc = M;
    long long outRow0 = 0;
    if constexpr (MODE==MRS) {
        segH0 = aH0 + (size_t)z*PP*CL;  segL0 = aL0 + (size_t)z*PP*CL;
        bHp   = bH  + (size_t)z*DD*CL;  bLp   = bL  + (size_t)z*DD*CL;
        Mloc = PP; outRow0 = (long long)z*PP;
    }

    f32x4 acc[MFR][NFR];
    #pragma unroll
    for (int i=0;i<MFR;++i)
        #pragma unroll
        for (int j=0;j<NFR;++j) acc[i][j] = f32x4{0.f,0.f,0.f,0.f};

    const int kbase = (MODE==MBIL) ? z*2048 : 0;
    const int nkt   = ((MODE==MBIL) ? 2048 : Ktot) / 32;

    for (int kt = 0; kt < nkt; ++kt) {
        const int k0 = kbase + kt*32;
        // ---- stage A ----
        if constexpr (MODE==MBIL) {
            int row = t>>2, koff = (t&3)*8;
            int gm = m0 + row;
            int k = k0 + koff;
            int hscol = k >> 6;                      // j*64 + a
            int tscol = ((k >> 12) << 6) + (k & 63); // j*64 + b
            u16x8 hv = Z8, lv = Z8;
            if (gm < Mloc) {
                float hsv = bf2f(aH0[(size_t)gm*DD + hscol]) + bf2f(aL0[(size_t)gm*DD + hscol]);
                u16x8 th = *(const u16x8*)(aH1 + (size_t)gm*DD + tscol);
                u16x8 tl = *(const u16x8*)(aL1 + (size_t)gm*DD + tscol);
                #pragma unroll
                for (int i2=0;i2<8;++i2){
                    float pr = hsv * (bf2f(th[i2]) + bf2f(tl[i2]));
                    u16 hh,ll; splitf_trunc(pr,hh,ll);
                    hv[i2]=hh; lv[i2]=ll;
                }
            }
            *(u16x8*)&AsH[row*KP + koff] = hv;
            *(u16x8*)&AsL[row*KP + koff] = lv;
        } else {
            int seg = (k0 >= 2*segsz) ? 2 : (k0 >= segsz ? 1 : 0);
            int soff = k0 - seg*segsz;
            const u16* pH = (seg==0)?segH0:(seg==1)?aH1:aH2;
            const u16* pL = (seg==0)?segL0:(seg==1)?aL1:aL2;
            if constexpr (BM==128) {
                int row = t>>1, koff = (t&1)*16;
                int gm = m0 + row;
                u16x8 h0=Z8,h1=Z8,l0=Z8,l1=Z8;
                if (gm < Mloc) {
                    const u16* ph = pH + (size_t)gm*segsz + soff + koff;
                    const u16* pl = pL + (size_t)gm*segsz + soff + koff;
                    h0 = *(const u16x8*)ph;  h1 = *(const u16x8*)(ph+8);
                    l0 = *(const u16x8*)pl;  l1 = *(const u16x8*)(pl+8);
                }
                *(u16x8*)&AsH[row*KP + koff]     = h0;
                *(u16x8*)&AsH[row*KP + koff + 8] = h1;
                *(u16x8*)&AsL[row*KP + koff]     = l0;
                *(u16x8*)&AsL[row*KP + koff + 8] = l1;
            } else {
                int row = t>>2, koff = (t&3)*8;
                int gm = m0 + row;
                u16x8 h0=Z8,l0=Z8;
                if (gm < Mloc) {
                    h0 = *(const u16x8*)(pH + (size_t)gm*segsz + soff + koff);
                    l0 = *(const u16x8*)(pL + (size_t)gm*segsz + soff + koff);
                }
                *(u16x8*)&AsH[row*KP + koff] = h0;
                *(u16x8*)&AsL[row*KP + koff] = l0;
            }
        }
        // ---- stage B (pre-split, pre-transposed [N][Ktot]) ----
        {
            if constexpr (BN==128) {
                int row = t>>1, koff = (t&1)*16;
                const u16* ph = bHp + (size_t)(n0+row)*Ktot + k0 + koff;
                const u16* pl = bLp + (size_t)(n0+row)*Ktot + k0 + koff;
                *(u16x8*)&BsH[row*KP + koff]     = *(const u16x8*)ph;
                *(u16x8*)&BsH[row*KP + koff + 8] = *(const u16x8*)(ph+8);
                *(u16x8*)&BsL[row*KP + koff]     = *(const u16x8*)pl;
                *(u16x8*)&BsL[row*KP + koff + 8] = *(const u16x8*)(pl+8);
            } else {
                int row = t>>2, koff = (t&3)*8;
                *(u16x8*)&BsH[row*KP + koff] = *(const u16x8*)(bHp + (size_t)(n0+row)*Ktot + k0 + koff);
                *(u16x8*)&BsL[row*KP + koff] = *(const u16x8*)(bLp + (size_t)(n0+row)*Ktot + k0 + koff);
            }
        }
        __syncthreads();
        // ---- MFMA ----
        {
            bf16x8 ah[MFR], al[MFR], bh[NFR], bl[NFR];
            #pragma unroll
            for (int mi=0;mi<MFR;++mi){
                int off = (wr*WM + mi*16 + lrow)*KP + lg*8;
                ah[mi] = *(const bf16x8*)&AsH[off];
                al[mi] = *(const bf16x8*)&AsL[off];
            }
            #pragma unroll
            for (int ni=0;ni<NFR;++ni){
                int off = (wc*64 + ni*16 + lrow)*KP + lg*8;
                bh[ni] = *(const bf16x8*)&BsH[off];
                bl[ni] = *(const bf16x8*)&BsL[off];
            }
            #pragma unroll
            for (int mi=0;mi<MFR;++mi)
                #pragma unroll
                for (int ni=0;ni<NFR;++ni){
                    acc[mi][ni] = __builtin_amdgcn_mfma_f32_16x16x32_bf16(ah[mi], bh[ni], acc[mi][ni], 0,0,0);
                    acc[mi][ni] = __builtin_amdgcn_mfma_f32_16x16x32_bf16(al[mi], bh[ni], acc[mi][ni], 0,0,0);
                    acc[mi][ni] = __builtin_amdgcn_mfma_f32_16x16x32_bf16(ah[mi], bl[ni], acc[mi][ni], 0,0,0);
                }
        }
        __syncthreads();
    }
    // ---- epilogue ----
    #pragma unroll
    for (int mi=0;mi<MFR;++mi)
        #pragma unroll
        for (int ni=0;ni<NFR;++ni)
            #pragma unroll
            for (int r=0;r<4;++r){
                int gm = m0 + wr*WM + mi*16 + lg*4 + r;
                int gn = n0 + wc*64 + ni*16 + lrow;
                if (gm >= Mloc) continue;
                float v = acc[mi][ni][r];
                if constexpr (MODE==MQW) {
                    oF[(size_t)gm*N + gn] = v;
                } else if constexpr (MODE==MSPLIT) {
                    v = fmaxf(v + bias[gn], 0.f);
                    u16 hh,ll; splitf(v,hh,ll);
                    oH[(size_t)gm*DD + gn] = hh;
                    oL[(size_t)gm*DD + gn] = ll;
                } else if constexpr (MODE==MRS) {
                    u16 hh,ll; splitf(v,hh,ll);
                    oH[(size_t)(outRow0+gm)*DD + gn] = hh;
                    oL[(size_t)(outRow0+gm)*DD + gn] = ll;
                } else {
                    if (gn < N) oF[((size_t)z*NPAIR + gm)*LOUT + gn] = v;
                }
            }
}

__global__ __launch_bounds__(256) void k_bilred(const float* __restrict__ partial,
                                                const float* __restrict__ bbil,
                                                float* __restrict__ out)
{
    int idx = blockIdx.x*blockDim.x + threadIdx.x;
    if (idx >= NPAIR*LOUT) return;
    int l = idx % LOUT;
    float s = bbil[l];
    #pragma unroll 4
    for (int sl=0; sl<24; ++sl) s += partial[(size_t)sl*NPAIR*LOUT + idx];
    out[idx] = s;
}

extern "C" void kernel_launch(void* const* d_in, const int* in_sizes, int n_in,
                              void* d_out, int out_size, void* d_ws, size_t ws_size,
                              hipStream_t stream)
{
    (void)in_sizes; (void)n_in; (void)out_size;
    const float* seq   = (const float*)d_in[0];
    const float* att   = (const float*)d_in[1];
    const int*   ms    = (const int*)d_in[2];
    const int*   hts   = (const int*)d_in[3];
    const float* Wm1   = (const float*)d_in[4];
    const float* Wm2   = (const float*)d_in[5];
    const float* bm    = (const float*)d_in[6];
    const float* Watt  = (const float*)d_in[7];
    const float* batt  = (const float*)d_in[8];
    const float* Wpath = (const float*)d_in[9];
    const float* bpath = (const float*)d_in[10];
    const float* Whead = (const float*)d_in[11];
    const float* bhead = (const float*)d_in[12];
    const float* Wtail = (const float*)d_in[13];
    const float* btail = (const float*)d_in[14];
    const float* Wbil  = (const float*)d_in[15];
    const float* bbil  = (const float*)d_in[16];
    float* out = (float*)d_out;

    // ---- workspace arena (all sizes 256-multiple). Peak ~99.96 MB. ----
    char* base = (char*)d_ws;
    size_t off = 0;
    auto take = [&](size_t bytes)->char* { char* r = base+off; off += bytes; return r; };
    // R0 region (aliased by WbilT after the path-GEMM)
    char*  R0      = base;
    float* edge    = (float*)take(4915200);     // 4*400*768*4
    float* qWb     = (float*)take(18677760);    // 1520*3072*4
    u16*   pathcH  = (u16*)  take(9338880);     // 1520*3072*2
    u16*   pathcL  = (u16*)  take(9338880);
    // persistent
    u16* nhH = (u16*)take(2334720);  u16* nhL = (u16*)take(2334720);   // 1520*768*2
    u16* ntH = (u16*)take(2334720);  u16* ntL = (u16*)take(2334720);
    u16* rsH = (u16*)take(2334720);  u16* rsL = (u16*)take(2334720);
    u16* pthH= (u16*)take(2334720);  u16* pthL= (u16*)take(2334720);
    u16* hsH = (u16*)take(2334720);  u16* hsL = (u16*)take(2334720);
    u16* tsH = (u16*)take(2334720);  u16* tsL = (u16*)take(2334720);
    float* glob = (float*)take(245760);
    float* Abuf = (float*)take(245760);
    float* Bbuf = (float*)take(245760);
    // R1 region (eatt+pa+seqT; aliased by WpathT after MRS)
    char*  R1     = base+off;
    float* eatt   = (float*)take(655360);       // 320*512*4
    u16*   paH    = (u16*)  take(1556480);      // 1520*512*2
    u16*   paL    = (u16*)  take(1556480);
    u16*   seqTH  = (u16*)  take(3145728);      // 4*768*512*2
    u16*   seqTL  = (u16*)  take(3145728);
    // R2 region (WattT; aliased by WheadT/WtailT after MQW, then part at MBIL)
    char*  R2     = base+off;
    u16*   WattTH = (u16*)  take(9437184);      // 3072*1536*2
    u16*   WattTL = (u16*)  take(9437184);
    size_t peak = off;
    if (peak > ws_size) return;   // fail loudly (out stays poisoned)

    // aliases
    u16* WpathTH = (u16*)R1;                        // 768*3072*2 = 4718592
    u16* WpathTL = (u16*)(R1 + 4718592);            // total 9437184 <= 10059776
    u16* WheadTH = (u16*)R2;                        // 768*2304*2 = 3538944
    u16* WheadTL = (u16*)(R2 + 3538944);
    u16* WtailTH = (u16*)(R2 + 7077888);
    u16* WtailTL = (u16*)(R2 + 10616832);           // total 14155776 <= 18874368
    float* part  = (float*)R2;                      // 24*1520*97*4 = 14154240 <= 18874368
    u16* WbilTH  = (u16*)R0;                        // 128*49152*2 = 12582912
    u16* WbilTL  = (u16*)(R0 + 12582912);           // total 25165824 <= 42270720

    // ---- weight conversions + prep ----
    k_wsplit<<<dim3(3072/64, 1536/64, 1), 256, 0, stream>>>(Watt, WattTH, WattTL, 1536, 3072, 0, 0);
    k_wsplit<<<dim3(768/64, 512/64, NDOC), 256, 0, stream>>>(seq, seqTH, seqTL, 512, 768,
                                                             (long long)CL*DD, (long long)DD*CL);
    k_prep<<<NDOC*EE*MM + NDOC*EE, 256, 0, stream>>>(att, seq, ms, eatt, glob);
    k_pairvec<<<NPAIR, 256, 0, stream>>>(seq, eatt, ms, hts, nhH, nhL, ntH, ntL, paH, paL);

    gemm_f32s<<<dim3(12, 1, NDOC), 256, 0, stream>>>(glob, DD, (long long)EE*DD, Wm1, DD,
                                                     Abuf, DD, (long long)EE*DD, EE, DD, DD);
    gemm_f32s<<<dim3(12, 1, NDOC), 256, 0, stream>>>(glob, DD, (long long)EE*DD, Wm2, DD,
                                                     Bbuf, DD, (long long)EE*DD, EE, DD, DD);
    k_edge<<<NDOC*EE*EE, 256, 0, stream>>>(Abuf, Bbuf, bm, edge);

    // rs = pa @ seq_i (MFMA, z=doc) -> rsH/L
    gemm_mfma<MRS,64,64><<<dim3(12, 6, NDOC), 256, 0, stream>>>(
        paH, paL, nullptr, nullptr, nullptr, nullptr, seqTH, seqTL, nullptr,
        nullptr, rsH, rsL, PP, DD, CL, CL);

    // WpathT conversion (overwrites eatt/pa/seqT -- all dead now)
    k_wsplit<<<dim3(768/64, 3072/64, 1), 256, 0, stream>>>(Wpath, WpathTH, WpathTL, 3072, 768, 0, 0);

    // qW = [nh|nt] @ Watt -> qWb (f32)
    gemm_mfma<MQW,128,128><<<dim3(3072/128, 12, 1), 256, 0, stream>>>(
        nhH, nhL, ntH, ntL, nullptr, nullptr, WattTH, WattTL, nullptr,
        qWb, nullptr, nullptr, NPAIR, 3072, 1536, DD);

    // WheadT/WtailT conversions (overwrite WattT -- dead now)
    k_wsplit<<<dim3(768/64, 2304/64, 1), 256, 0, stream>>>(Whead, WheadTH, WheadTL, 2304, 768, 0, 0);
    k_wsplit<<<dim3(768/64, 2304/64, 1), 256, 0, stream>>>(Wtail, WtailTH, WtailTL, 2304, 768, 0, 0);

    k_scorepath<<<NPAIR, 256, 0, stream>>>(qWb, edge, hts, batt, pathcH, pathcL);

    // path = relu(pathc @ Wpath + bpath) -> pthH/L
    gemm_mfma<MSPLIT,64,64><<<dim3(12, 24, 1), 256, 0, stream>>>(
        pathcH, pathcL, nullptr, nullptr, nullptr, nullptr, WpathTH, WpathTL, bpath,
        nullptr, pthH, pthL, NPAIR, DD, 3072, 3072);

    // WbilT conversion (overwrites edge/qWb/pathcH -- dead now)
    k_wsplit<<<dim3(128/64, 49152/64, 1), 256, 0, stream>>>(Wbil, WbilTH, WbilTL, 49152, LOUT, 0, 0);

    // hs = relu([nh|rs|path] @ Whead + bhead) ; ts = relu([nt|rs|path] @ Wtail + btail)
    gemm_mfma<MSPLIT,64,64><<<dim3(12, 24, 1), 256, 0, stream>>>(
        nhH, nhL, rsH, rsL, pthH, pthL, WheadTH, WheadTL, bhead,
        nullptr, hsH, hsL, NPAIR, DD, 2304, DD);
    gemm_mfma<MSPLIT,64,64><<<dim3(12, 24, 1), 256, 0, stream>>>(
        ntH, ntL, rsH, rsL, pthH, pthL, WtailTH, WtailTL, btail,
        nullptr, tsH, tsL, NPAIR, DD, 2304, DD);

    // bilinear: product tiles on the fly, K chunked x24 -> part (overwrites Whead/Wtail region)
    gemm_mfma<MBIL,64,128><<<dim3(1, 24, 24), 256, 0, stream>>>(
        hsH, hsL, tsH, tsL, nullptr, nullptr, WbilTH, WbilTL, nullptr,
        part, nullptr, nullptr, NPAIR, LOUT, 49152, 49152);

    k_bilred<<<(NPAIR*LOUT+255)/256, 256, 0, stream>>>(part, bbil, out);
}

// Round 6
// 726.759 us; speedup vs baseline: 2.2392x; 1.0671x over previous
//
#include <hip/hip_runtime.h>
#include <hip/hip_bf16.h>

#define NDOC 4
#define CL   512
#define DD   768
#define HH   12
#define EE   20
#define MM   4
#define PP   380
#define NPAIR 1520
#define LOUT 97
#define KP   40   // padded LDS row (u16) for 32-wide k slabs (80 B rows)
#define KP2  72   // padded LDS row (u16) for 64-wide k slabs (144 B rows)

typedef unsigned short u16;
typedef short bf16x8 __attribute__((ext_vector_type(8)));
typedef u16   u16x8  __attribute__((ext_vector_type(8)));
typedef u16   u16x4  __attribute__((ext_vector_type(4)));
typedef float f32x4  __attribute__((ext_vector_type(4)));

#define Z8 (u16x8){0,0,0,0,0,0,0,0}

__device__ __forceinline__ u16 f2bf(float x){
    union { float f; unsigned u; } v; v.f = x;
    return (u16)((v.u + 0x7fffu + ((v.u >> 16) & 1u)) >> 16);
}
__device__ __forceinline__ float bf2f(u16 h){
    union { unsigned u; float f; } v; v.u = ((unsigned)h) << 16;
    return v.f;
}
__device__ __forceinline__ void splitf(float x, u16 &h, u16 &l){
    h = f2bf(x);
    l = f2bf(x - bf2f(h));
}

// ---------------------------------------------------------------------------
// transpose + split: W [K][N] f32 -> WH/WL [Npad][K] u16 (rows >= N zero-filled)
__global__ __launch_bounds__(256) void k_wsplit(const float* __restrict__ W,
                                                u16* __restrict__ WH, u16* __restrict__ WL,
                                                int K, int N, long long srcStride,
                                                long long dstStride)
{
    __shared__ u16 tH[64][66], tL[64][66];
    const float* Wp = W + (size_t)blockIdx.z*srcStride;
    u16* WHp = WH + (size_t)blockIdx.z*dstStride;
    u16* WLp = WL + (size_t)blockIdx.z*dstStride;
    int n0 = blockIdx.x*64, k0 = blockIdx.y*64;
    int t = threadIdx.x;
    int kr = t>>4, c4 = (t&15)*4;
    bool vec4 = ((N & 3) == 0);
    #pragma unroll
    for (int rr=0; rr<4; ++rr) {
        int k = k0 + kr + rr*16;
        float arr[4];
        if (vec4 && n0 + c4 + 3 < N) {
            float4 v = *(const float4*)(Wp + (size_t)k*N + n0 + c4);
            arr[0]=v.x; arr[1]=v.y; arr[2]=v.z; arr[3]=v.w;
        } else {
            #pragma unroll
            for (int i=0;i<4;++i){ int n=n0+c4+i; arr[i] = (n<N)? Wp[(size_t)k*N+n] : 0.f; }
        }
        #pragma unroll
        for (int i=0;i<4;++i){
            u16 hh,ll; splitf(arr[i],hh,ll);
            tH[c4+i][kr+rr*16] = hh;
            tL[c4+i][kr+rr*16] = ll;
        }
    }
    __syncthreads();
    int nr = t>>4, kc = (t&15)*4;
    #pragma unroll
    for (int rr=0; rr<4; ++rr) {
        int nl = nr + rr*16;
        u16x4 vh, vl;
        #pragma unroll
        for (int i=0;i<4;++i){ vh[i]=tH[nl][kc+i]; vl[i]=tL[nl][kc+i]; }
        size_t o = (size_t)(n0+nl)*K + k0 + kc;
        *(u16x4*)(WHp + o) = vh;
        *(u16x4*)(WLp + o) = vl;
    }
}

// ---------------------------------------------------------------------------
// prep: blocks [0,320): eatt rows; [320,400): glob rows
__global__ __launch_bounds__(256) void k_prep(const float* __restrict__ att,
                                              const float* __restrict__ seq,
                                              const int* __restrict__ ms,
                                              float* __restrict__ eatt,
                                              float* __restrict__ glob)
{
    int b = blockIdx.x;
    if (b < NDOC*EE*MM) {
        int row = b;
        int i = row / (EE*MM);
        int pos = ms[row] + 1;
        const float* base = att + ((size_t)i*HH)*CL*CL + (size_t)pos*CL;
        for (int c = threadIdx.x; c < CL; c += 256) {
            float s = 0.f;
            #pragma unroll
            for (int h = 0; h < HH; ++h) s += base[(size_t)h*CL*CL + c];
            eatt[(size_t)row*CL + c] = s * (1.0f/HH);
        }
    } else {
        int ie = b - NDOC*EE*MM;
        int i = ie / EE;
        const int* mp = ms + ie*MM;
        const float* sb = seq + (size_t)i*CL*DD;
        const float* r0 = sb + (size_t)(mp[0]+1)*DD;
        const float* r1 = sb + (size_t)(mp[1]+1)*DD;
        const float* r2 = sb + (size_t)(mp[2]+1)*DD;
        const float* r3 = sb + (size_t)(mp[3]+1)*DD;
        for (int d = threadIdx.x; d < DD; d += 256) {
            float a=r0[d], bb=r1[d], c=r2[d], e=r3[d];
            float mx = fmaxf(fmaxf(a,bb), fmaxf(c,e));
            float s = expf(a-mx)+expf(bb-mx)+expf(c-mx)+expf(e-mx);
            glob[(size_t)ie*DD + d] = mx + logf(s);
        }
    }
}

// per pair: pair weights inline; nh/nt (bf16 hi/lo), pa (bf16 hi/lo)
__global__ __launch_bounds__(256) void k_pairvec(const float* __restrict__ seq,
                                                 const float* __restrict__ eatt,
                                                 const int* __restrict__ ms,
                                                 const int* __restrict__ hts,
                                                 u16* __restrict__ nhH, u16* __restrict__ nhL,
                                                 u16* __restrict__ ntH, u16* __restrict__ ntL,
                                                 u16* __restrict__ paH, u16* __restrict__ paL)
{
    int g = blockIdx.x;
    int i = g / PP;
    int h = hts[2*g], t = hts[2*g+1];
    const float* eh = eatt + (size_t)(i*EE+h)*MM*CL;
    const float* et = eatt + (size_t)(i*EE+t)*MM*CL;
    int ph[MM], pt[MM];
    #pragma unroll
    for (int m=0;m<MM;++m){ ph[m]=ms[(i*EE+h)*MM+m]+1; pt[m]=ms[(i*EE+t)*MM+m]+1; }
    float pH[MM], pT[MM]; float sh=0.f, st=0.f;
    #pragma unroll
    for (int m2=0; m2<MM; ++m2) {
        float s = 0.f, s2 = 0.f;
        #pragma unroll
        for (int m=0;m<MM;++m) { s += eh[m*CL + pt[m2]]; s2 += et[m*CL + ph[m2]]; }
        pH[m2] = s*0.25f;  sh += pH[m2];
        pT[m2] = s2*0.25f; st += pT[m2];
    }
    float rh = 1.f/(sh+1e-5f), rt = 1.f/(st+1e-5f);
    #pragma unroll
    for (int m=0;m<MM;++m){ pH[m]*=rh; pT[m]*=rt; }

    const float* sb = seq + (size_t)i*CL*DD;
    for (int d = threadIdx.x; d < DD; d += 256) {
        float nh = pT[0]*sb[(size_t)ph[0]*DD+d] + pT[1]*sb[(size_t)ph[1]*DD+d]
                 + pT[2]*sb[(size_t)ph[2]*DD+d] + pT[3]*sb[(size_t)ph[3]*DD+d];
        float nt = pH[0]*sb[(size_t)pt[0]*DD+d] + pH[1]*sb[(size_t)pt[1]*DD+d]
                 + pH[2]*sb[(size_t)pt[2]*DD+d] + pH[3]*sb[(size_t)pt[3]*DD+d];
        u16 hh,ll;
        splitf(nh,hh,ll);
        nhH[(size_t)g*DD + d]=hh; nhL[(size_t)g*DD + d]=ll;
        splitf(nt,hh,ll);
        ntH[(size_t)g*DD + d]=hh; ntL[(size_t)g*DD + d]=ll;
    }
    float vv[2]; float lsum = 0.f;
    #pragma unroll
    for (int it=0; it<2; ++it) {
        int c = threadIdx.x + it*256;
        float na = pT[0]*eh[c] + pT[1]*eh[CL+c] + pT[2]*eh[2*CL+c] + pT[3]*eh[3*CL+c];
        float nb = pH[0]*et[c] + pH[1]*et[CL+c] + pH[2]*et[2*CL+c] + pH[3]*et[3*CL+c];
        vv[it] = na*nb; lsum += vv[it];
    }
    float tot = lsum;
    #pragma unroll
    for (int o=32;o;o>>=1) tot += __shfl_xor(tot, o);
    __shared__ float wsum[4];
    if ((threadIdx.x & 63)==0) wsum[threadIdx.x>>6] = tot;
    __syncthreads();
    float inv = 1.f/(wsum[0]+wsum[1]+wsum[2]+wsum[3] + 1e-5f);
    #pragma unroll
    for (int it=0; it<2; ++it){
        int c = threadIdx.x + it*256;
        u16 hh,ll; splitf(vv[it]*inv,hh,ll);
        paH[(size_t)g*CL + c]=hh; paL[(size_t)g*CL + c]=ll;
    }
}

// edge = relu(A[h] + B[t] + bm)
__global__ __launch_bounds__(256) void k_edge(const float* __restrict__ Ab,
                                              const float* __restrict__ Bb,
                                              const float* __restrict__ bm,
                                              float* __restrict__ edge)
{
    int iht = blockIdx.x;
    int i = iht/(EE*EE); int rem = iht%(EE*EE); int h = rem/EE; int tt = rem%EE;
    const float* a = Ab + (size_t)(i*EE+h)*DD;
    const float* b = Bb + (size_t)(i*EE+tt)*DD;
    float* e = edge + (size_t)iht*DD;
    for (int d=threadIdx.x; d<DD; d+=256)
        e[d] = fmaxf(a[d]+b[d]+bm[d], 0.f);
}

// score (4 einsums) -> masked softmax -> path rows (bf16 hi/lo)
__global__ __launch_bounds__(256) void k_scorepath(const float* __restrict__ qW,
                                                   const float* __restrict__ edge,
                                                   const int* __restrict__ hts,
                                                   const float* __restrict__ battp,
                                                   u16* __restrict__ pathcH,
                                                   u16* __restrict__ pathcL)
{
    int g = blockIdx.x;
    int i = g / PP;
    int h = hts[2*g], t = hts[2*g+1];
    __shared__ float qs[4*DD];
    __shared__ float sc[EE];
    __shared__ float aw[EE];
    for (int d4 = threadIdx.x; d4 < DD; d4 += 256)
        *(float4*)&qs[d4*4] = *(const float4*)(qW + (size_t)g*3072 + d4*4);
    __syncthreads();
    const float* eb = edge + (size_t)i*EE*EE*DD;
    int lane = threadIdx.x & 63, wid = threadIdx.x >> 6;
    for (int v = wid; v < EE; v += 4) {
        const float* e1 = eb + (size_t)(h*EE+v)*DD;
        const float* e2 = eb + (size_t)(v*EE+t)*DD;
        const float* e3 = eb + (size_t)(t*EE+v)*DD;
        const float* e4 = eb + (size_t)(v*EE+h)*DD;
        float s = 0.f;
        for (int d = lane; d < DD; d += 64)
            s += qs[d]*e1[d] + qs[DD+d]*e2[d] + qs[2*DD+d]*e3[d] + qs[3*DD+d]*e4[d];
        #pragma unroll
        for (int o=32;o;o>>=1) s += __shfl_xor(s, o);
        if (lane==0) sc[v] = s + battp[0];
    }
    __syncthreads();
    if (threadIdx.x == 0) {
        float mx = -3.0e38f;
        for (int v=0;v<EE;++v){ float x = (v==h||v==t)? -1e30f : sc[v]; sc[v]=x; mx = fmaxf(mx,x); }
        float su=0.f;
        for (int v=0;v<EE;++v){ float e = expf(sc[v]-mx); aw[v]=e; su+=e; }
        float inv = 1.f/su;
        for (int v=0;v<EE;++v) aw[v]*=inv;
    }
    __syncthreads();
    for (int idx = threadIdx.x; idx < 4*DD; idx += 256) {
        int k = idx / DD, d = idx % DD;
        const float* e;
        int stride;
        if (k==0)      { e = eb + (size_t)h*EE*DD + d; stride = DD; }
        else if (k==1) { e = eb + (size_t)t*DD + d;     stride = EE*DD; }
        else if (k==2) { e = eb + (size_t)t*EE*DD + d;  stride = DD; }
        else           { e = eb + (size_t)h*DD + d;     stride = EE*DD; }
        float s = 0.f;
        #pragma unroll
        for (int v=0; v<EE; ++v) s += aw[v]*e[(size_t)v*stride];
        u16 hh,ll; splitf(s,hh,ll);
        pathcH[(size_t)g*3072 + idx] = hh;
        pathcL[(size_t)g*3072 + idx] = ll;
    }
}

// merged small f32 GEMM: z = doc*2 + sel; A=glob[doc], B = sel?Wm2:Wm1, C = sel?Bbuf:Abuf
__global__ __launch_bounds__(256) void gemm_f32s(const float* __restrict__ glob,
                                                 const float* __restrict__ W1,
                                                 const float* __restrict__ W2,
                                                 float* __restrict__ C1,
                                                 float* __restrict__ C2)
{
    int doc = blockIdx.z >> 1, sel = blockIdx.z & 1;
    const float* A = glob + (size_t)doc*EE*DD;
    const float* B = sel ? W2 : W1;
    float* C = (sel ? C2 : C1) + (size_t)doc*EE*DD;
    __shared__ float As[16][68];
    __shared__ float Bs[16][68];
    int n0 = blockIdx.x*64;
    int t = threadIdx.x;
    int tx = t & 15, ty = t >> 4;
    int am = t >> 2, ac = (t & 3) * 4;
    int bk = t >> 4, bn = (t & 15) * 4;
    float acc[4][4] = {};
    for (int k0 = 0; k0 < DD; k0 += 16) {
        float4 av = make_float4(0,0,0,0);
        if (am < EE) av = *reinterpret_cast<const float4*>(A + (size_t)am*DD + k0 + ac);
        As[ac+0][am]=av.x; As[ac+1][am]=av.y; As[ac+2][am]=av.z; As[ac+3][am]=av.w;
        float4 bv = *reinterpret_cast<const float4*>(B + (size_t)(k0+bk)*DD + n0 + bn);
        *reinterpret_cast<float4*>(&Bs[bk][bn]) = bv;
        __syncthreads();
        #pragma unroll
        for (int kk=0; kk<16; ++kk) {
            const float4 a = *reinterpret_cast<const float4*>(&As[kk][ty*4]);
            const float4 b = *reinterpret_cast<const float4*>(&Bs[kk][tx*4]);
            float ar[4] = {a.x,a.y,a.z,a.w};
            float br[4] = {b.x,b.y,b.z,b.w};
            #pragma unroll
            for (int r=0;r<4;++r)
                #pragma unroll
                for (int c2=0;c2<4;++c2) acc[r][c2] = fmaf(ar[r], br[c2], acc[r][c2]);
        }
        __syncthreads();
    }
    #pragma unroll
    for (int r=0;r<4;++r) {
        int gm = ty*4 + r;
        if (gm >= EE) continue;
        #pragma unroll
        for (int c2=0;c2<4;++c2)
            C[(size_t)gm*DD + n0 + tx*4 + c2] = acc[r][c2];
    }
}

// ---------------------------------------------------------------------------
// Split-bf16 MFMA GEMM. A: segmented [M][segsz] bf16 hi/lo. B: pre-split
// pre-transposed [N][Ktot]. 3 MFMAs/frag-pair: hi*hi + lo*hi + hi*lo.
// MHT: z selects {head: seg0=nh, B=Whead, out=f32 hsF} / {tail: seg0=nt, B=Wtail, out=split ts}.
enum { MQW=0, MSPLIT=1, MRS=2, MHT=3 };

template<int MODE, int BM, int BN>
__global__ __launch_bounds__(256) void gemm_mfma(
    const u16* __restrict__ aH0, const u16* __restrict__ aL0,
    const u16* __restrict__ aH1, const u16* __restrict__ aL1,
    const u16* __restrict__ aH2, const u16* __restrict__ aL2,
    const u16* __restrict__ a0bH, const u16* __restrict__ a0bL,
    const u16* __restrict__ bH, const u16* __restrict__ bL,
    const u16* __restrict__ bHb, const u16* __restrict__ bLb,
    const float* __restrict__ bias, const float* __restrict__ biasb,
    float* __restrict__ oF,
    u16* __restrict__ oH, u16* __restrict__ oL,
    u16* __restrict__ oHb, u16* __restrict__ oLb,
    int M, int N, int Ktot, int segsz)
{
    constexpr int NWN = BN/64;
    constexpr int NWM = 4/NWN;
    constexpr int WM  = BM/NWM;
    constexpr int MFR = WM/16;
    constexpr int NFR = 4;
    __shared__ u16 AsH[BM*KP], AsL[BM*KP], BsH[BN*KP], BsL[BN*KP];

    const int t = threadIdx.x;
    const int z = blockIdx.z;
    const int m0 = blockIdx.y*BM, n0 = blockIdx.x*BN;
    const int lane = t & 63, wid = t >> 6;
    const int wr = wid / NWN, wc = wid % NWN;
    const int lrow = lane & 15, lg = lane >> 4;

    const u16 *segH0=aH0, *segL0=aL0;
    const u16 *bHp = bH, *bLp = bL;
    const float* bp = bias;
    float* fOut = nullptr;
    u16 *hOut = oH, *lOut = oL;
    int Mloc = M;
    long long outRow0 = 0;
    if constexpr (MODE==MRS) {
        segH0 = aH0 + (size_t)z*PP*CL;  segL0 = aL0 + (size_t)z*PP*CL;
        bHp   = bH  + (size_t)z*DD*CL;  bLp   = bL  + (size_t)z*DD*CL;
        Mloc = PP; outRow0 = (long long)z*PP;
    }
    if constexpr (MODE==MHT) {
        if (z == 0) { fOut = oF; hOut = nullptr; lOut = nullptr; }
        else { segH0 = a0bH; segL0 = a0bL; bHp = bHb; bLp = bLb; bp = biasb;
               hOut = oHb; lOut = oLb; }
    }

    f32x4 acc[MFR][NFR];
    #pragma unroll
    for (int i=0;i<MFR;++i)
        #pragma unroll
        for (int j=0;j<NFR;++j) acc[i][j] = f32x4{0.f,0.f,0.f,0.f};

    const int nkt = Ktot / 32;

    for (int kt = 0; kt < nkt; ++kt) {
        const int k0 = kt*32;
        // ---- stage A ----
        {
            int seg = (k0 >= 2*segsz) ? 2 : (k0 >= segsz ? 1 : 0);
            int soff = k0 - seg*segsz;
            const u16* pH = (seg==0)?segH0:(seg==1)?aH1:aH2;
            const u16* pL = (seg==0)?segL0:(seg==1)?aL1:aL2;
            if constexpr (BM==128) {
                int row = t>>1, koff = (t&1)*16;
                int gm = m0 + row;
                u16x8 h0=Z8,h1=Z8,l0=Z8,l1=Z8;
                if (gm < Mloc) {
                    const u16* ph = pH + (size_t)gm*segsz + soff + koff;
                    const u16* pl = pL + (size_t)gm*segsz + soff + koff;
                    h0 = *(const u16x8*)ph;  h1 = *(const u16x8*)(ph+8);
                    l0 = *(const u16x8*)pl;  l1 = *(const u16x8*)(pl+8);
                }
                *(u16x8*)&AsH[row*KP + koff]     = h0;
                *(u16x8*)&AsH[row*KP + koff + 8] = h1;
                *(u16x8*)&AsL[row*KP + koff]     = l0;
                *(u16x8*)&AsL[row*KP + koff + 8] = l1;
            } else {
                int row = t>>2, koff = (t&3)*8;
                int gm = m0 + row;
                u16x8 h0=Z8,l0=Z8;
                if (gm < Mloc) {
                    h0 = *(const u16x8*)(pH + (size_t)gm*segsz + soff + koff);
                    l0 = *(const u16x8*)(pL + (size_t)gm*segsz + soff + koff);
                }
                *(u16x8*)&AsH[row*KP + koff] = h0;
                *(u16x8*)&AsL[row*KP + koff] = l0;
            }
        }
        // ---- stage B ----
        {
            if constexpr (BN==128) {
                int row = t>>1, koff = (t&1)*16;
                const u16* ph = bHp + (size_t)(n0+row)*Ktot + k0 + koff;
                const u16* pl = bLp + (size_t)(n0+row)*Ktot + k0 + koff;
                *(u16x8*)&BsH[row*KP + koff]     = *(const u16x8*)ph;
                *(u16x8*)&BsH[row*KP + koff + 8] = *(const u16x8*)(ph+8);
                *(u16x8*)&BsL[row*KP + koff]     = *(const u16x8*)pl;
                *(u16x8*)&BsL[row*KP + koff + 8] = *(const u16x8*)(pl+8);
            } else {
                int row = t>>2, koff = (t&3)*8;
                *(u16x8*)&BsH[row*KP + koff] = *(const u16x8*)(bHp + (size_t)(n0+row)*Ktot + k0 + koff);
                *(u16x8*)&BsL[row*KP + koff] = *(const u16x8*)(bLp + (size_t)(n0+row)*Ktot + k0 + koff);
            }
        }
        __syncthreads();
        // ---- MFMA ----
        {
            bf16x8 ah[MFR], al[MFR], bh[NFR], bl[NFR];
            #pragma unroll
            for (int mi=0;mi<MFR;++mi){
                int off = (wr*WM + mi*16 + lrow)*KP + lg*8;
                ah[mi] = *(const bf16x8*)&AsH[off];
                al[mi] = *(const bf16x8*)&AsL[off];
            }
            #pragma unroll
            for (int ni=0;ni<NFR;++ni){
                int off = (wc*64 + ni*16 + lrow)*KP + lg*8;
                bh[ni] = *(const bf16x8*)&BsH[off];
                bl[ni] = *(const bf16x8*)&BsL[off];
            }
            #pragma unroll
            for (int mi=0;mi<MFR;++mi)
                #pragma unroll
                for (int ni=0;ni<NFR;++ni){
                    acc[mi][ni] = __builtin_amdgcn_mfma_f32_16x16x32_bf16(ah[mi], bh[ni], acc[mi][ni], 0,0,0);
                    acc[mi][ni] = __builtin_amdgcn_mfma_f32_16x16x32_bf16(al[mi], bh[ni], acc[mi][ni], 0,0,0);
                    acc[mi][ni] = __builtin_amdgcn_mfma_f32_16x16x32_bf16(ah[mi], bl[ni], acc[mi][ni], 0,0,0);
                }
        }
        __syncthreads();
    }
    // ---- epilogue ----
    #pragma unroll
    for (int mi=0;mi<MFR;++mi)
        #pragma unroll
        for (int ni=0;ni<NFR;++ni)
            #pragma unroll
            for (int r=0;r<4;++r){
                int gm = m0 + wr*WM + mi*16 + lg*4 + r;
                int gn = n0 + wc*64 + ni*16 + lrow;
                if (gm >= Mloc) continue;
                float v = acc[mi][ni][r];
                if constexpr (MODE==MQW) {
                    oF[(size_t)gm*N + gn] = v;
                } else if constexpr (MODE==MRS) {
                    u16 hh,ll; splitf(v,hh,ll);
                    oH[(size_t)(outRow0+gm)*DD + gn] = hh;
                    oL[(size_t)(outRow0+gm)*DD + gn] = ll;
                } else {
                    v = fmaxf(v + bp[gn], 0.f);
                    if (fOut) fOut[(size_t)gm*DD + gn] = v;
                    if (hOut) {
                        u16 hh,ll; splitf(v,hh,ll);
                        hOut[(size_t)gm*DD + gn] = hh;
                        lOut[(size_t)gm*DD + gn] = ll;
                    }
                }
            }
}

// ---------------------------------------------------------------------------
// Bilinear via triple-product factorization:
// out[m,l] = sum_{j,a} hsF[m,ja] * ( sum_b ts[m,jb] * WbilT[l, j*4096+a*64+b] )
// Inner sum = K=64 MFMA contraction (A = ts hi/lo, staged once per block;
// B = WbilT slab per a). hs applied as exact f32 per-row scale post-MFMA.
// grid (1, 12, 48): y = m-block (128), z = (j, a-quarter 16).
__global__ __launch_bounds__(256) void k_bil2(const u16* __restrict__ tsH,
                                              const u16* __restrict__ tsL,
                                              const float* __restrict__ hsF,
                                              const u16* __restrict__ WH,
                                              const u16* __restrict__ WL,
                                              float* __restrict__ out)
{
    __shared__ u16 TsH[128*KP2], TsL[128*KP2];
    __shared__ u16 BbH[128*KP], BbL[128*KP];
    const int t = threadIdx.x;
    const int m0 = blockIdx.y*128;
    const int z = blockIdx.z;
    const int j = z>>2, a0 = (z&3)*16;
    const int lane = t & 63, wid = t >> 6;
    const int wr = wid >> 1, wc = wid & 1;      // 2x2 wave grid (WM=64, WN=64)
    const int lrow = lane & 15, lg = lane >> 4;

    // stage ts slab [128][64] hi/lo once
    {
        int row = t>>1, half = t&1;
        int gm = m0 + row;
        int col = j*64 + half*32;
        u16x8 h0=Z8,h1=Z8,h2=Z8,h3=Z8,l0=Z8,l1=Z8,l2=Z8,l3=Z8;
        if (gm < NPAIR) {
            const u16* ph = tsH + (size_t)gm*DD + col;
            const u16* pl = tsL + (size_t)gm*DD + col;
            h0=*(const u16x8*)ph;      h1=*(const u16x8*)(ph+8);
            h2=*(const u16x8*)(ph+16); h3=*(const u16x8*)(ph+24);
            l0=*(const u16x8*)pl;      l1=*(const u16x8*)(pl+8);
            l2=*(const u16x8*)(pl+16); l3=*(const u16x8*)(pl+24);
        }
        int o = row*KP2 + half*32;
        *(u16x8*)&TsH[o]=h0;    *(u16x8*)&TsH[o+8]=h1;
        *(u16x8*)&TsH[o+16]=h2; *(u16x8*)&TsH[o+24]=h3;
        *(u16x8*)&TsL[o]=l0;    *(u16x8*)&TsL[o+8]=l1;
        *(u16x8*)&TsL[o+16]=l2; *(u16x8*)&TsL[o+24]=l3;
    }

    f32x4 facc[4][4];
    #pragma unroll
    for (int mi=0;mi<4;++mi)
        #pragma unroll
        for (int ni=0;ni<4;++ni) facc[mi][ni] = f32x4{0.f,0.f,0.f,0.f};

    for (int ai=0; ai<16; ++ai) {
        int a = a0 + ai;
        f32x4 tacc[4][4];
        #pragma unroll
        for (int mi=0;mi<4;++mi)
            #pragma unroll
            for (int ni=0;ni<4;++ni) tacc[mi][ni] = f32x4{0.f,0.f,0.f,0.f};
        #pragma unroll
        for (int half=0; half<2; ++half) {
            __syncthreads();   // protects B slab (and Ts on first iteration)
            {   // stage B slab [128 l][32 b] hi/lo
                int row = t>>1, h2 = t&1;
                size_t src = (size_t)row*49152 + (size_t)j*4096 + (size_t)a*64 + half*32 + h2*16;
                *(u16x8*)&BbH[row*KP + h2*16]     = *(const u16x8*)(WH + src);
                *(u16x8*)&BbH[row*KP + h2*16 + 8] = *(const u16x8*)(WH + src + 8);
                *(u16x8*)&BbL[row*KP + h2*16]     = *(const u16x8*)(WL + src);
                *(u16x8*)&BbL[row*KP + h2*16 + 8] = *(const u16x8*)(WL + src + 8);
            }
            __syncthreads();
            bf16x8 ah[4], al[4], bh[4], bl[4];
            #pragma unroll
            for (int mi=0;mi<4;++mi){
                int off = (wr*64 + mi*16 + lrow)*KP2 + half*32 + lg*8;
                ah[mi] = *(const bf16x8*)&TsH[off];
                al[mi] = *(const bf16x8*)&TsL[off];
            }
            #pragma unroll
            for (int ni=0;ni<4;++ni){
                int off = (wc*64 + ni*16 + lrow)*KP + lg*8;
                bh[ni] = *(const bf16x8*)&BbH[off];
                bl[ni] = *(const bf16x8*)&BbL[off];
            }
            #pragma unroll
            for (int mi=0;mi<4;++mi)
                #pragma unroll
                for (int ni=0;ni<4;++ni){
                    tacc[mi][ni] = __builtin_amdgcn_mfma_f32_16x16x32_bf16(ah[mi], bh[ni], tacc[mi][ni], 0,0,0);
                    tacc[mi][ni] = __builtin_amdgcn_mfma_f32_16x16x32_bf16(al[mi], bh[ni], tacc[mi][ni], 0,0,0);
                    tacc[mi][ni] = __builtin_amdgcn_mfma_f32_16x16x32_bf16(ah[mi], bl[ni], tacc[mi][ni], 0,0,0);
                }
        }
        // exact f32 scale by hs[m, j*64+a], accumulate
        float hv[4][4];
        #pragma unroll
        for (int mi=0;mi<4;++mi)
            #pragma unroll
            for (int r=0;r<4;++r){
                int gm = m0 + wr*64 + mi*16 + lg*4 + r;
                hv[mi][r] = (gm < NPAIR) ? hsF[(size_t)gm*DD + j*64 + a] : 0.f;
            }
        #pragma unroll
        for (int mi=0;mi<4;++mi)
            #pragma unroll
            for (int ni=0;ni<4;++ni)
                #pragma unroll
                for (int r=0;r<4;++r)
                    facc[mi][ni][r] = fmaf(hv[mi][r], tacc[mi][ni][r], facc[mi][ni][r]);
    }
    // atomic accumulate into out
    #pragma unroll
    for (int mi=0;mi<4;++mi)
        #pragma unroll
        for (int ni=0;ni<4;++ni)
            #pragma unroll
            for (int r=0;r<4;++r){
                int gm = m0 + wr*64 + mi*16 + lg*4 + r;
                int gn = wc*64 + ni*16 + lrow;
                if (gm < NPAIR && gn < LOUT)
                    atomicAdd(&out[(size_t)gm*LOUT + gn], facc[mi][ni][r]);
            }
}

__global__ __launch_bounds__(256) void k_outinit(const float* __restrict__ bbil,
                                                 float* __restrict__ out)
{
    int idx = blockIdx.x*blockDim.x + threadIdx.x;
    if (idx >= NPAIR*LOUT) return;
    out[idx] = bbil[idx % LOUT];
}

extern "C" void kernel_launch(void* const* d_in, const int* in_sizes, int n_in,
                              void* d_out, int out_size, void* d_ws, size_t ws_size,
                              hipStream_t stream)
{
    (void)in_sizes; (void)n_in; (void)out_size;
    const float* seq   = (const float*)d_in[0];
    const float* att   = (const float*)d_in[1];
    const int*   ms    = (const int*)d_in[2];
    const int*   hts   = (const int*)d_in[3];
    const float* Wm1   = (const float*)d_in[4];
    const float* Wm2   = (const float*)d_in[5];
    const float* bm    = (const float*)d_in[6];
    const float* Watt  = (const float*)d_in[7];
    const float* batt  = (const float*)d_in[8];
    const float* Wpath = (const float*)d_in[9];
    const float* bpath = (const float*)d_in[10];
    const float* Whead = (const float*)d_in[11];
    const float* bhead = (const float*)d_in[12];
    const float* Wtail = (const float*)d_in[13];
    const float* btail = (const float*)d_in[14];
    const float* Wbil  = (const float*)d_in[15];
    const float* bbil  = (const float*)d_in[16];
    float* out = (float*)d_out;

    // ---- workspace arena ----
    char* base = (char*)d_ws;
    size_t off = 0;
    auto take = [&](size_t bytes)->char* { char* r = base+off; off += bytes; return r; };
    // R0 region (aliased by WbilT after the path-GEMM)
    char*  R0      = base;
    float* edge    = (float*)take(4915200);     // 4*400*768*4
    float* qWb     = (float*)take(18677760);    // 1520*3072*4
    u16*   pathcH  = (u16*)  take(9338880);     // 1520*3072*2
    u16*   pathcL  = (u16*)  take(9338880);
    // persistent
    u16* nhH = (u16*)take(2334720);  u16* nhL = (u16*)take(2334720);   // 1520*768*2
    u16* ntH = (u16*)take(2334720);  u16* ntL = (u16*)take(2334720);
    u16* rsH = (u16*)take(2334720);  u16* rsL = (u16*)take(2334720);
    u16* pthH= (u16*)take(2334720);  u16* pthL= (u16*)take(2334720);
    u16* tsH = (u16*)take(2334720);  u16* tsL = (u16*)take(2334720);
    float* hsF = (float*)take(4669440);         // 1520*768*4
    float* glob = (float*)take(245760);
    float* Abuf = (float*)take(245760);
    float* Bbuf = (float*)take(245760);
    // R1 region (eatt+pa+seqT; aliased by WpathT after MRS)
    char*  R1     = base+off;
    float* eatt   = (float*)take(655360);       // 320*512*4
    u16*   paH    = (u16*)  take(1556480);      // 1520*512*2
    u16*   paL    = (u16*)  take(1556480);
    u16*   seqTH  = (u16*)  take(3145728);      // 4*768*512*2
    u16*   seqTL  = (u16*)  take(3145728);
    // R2 region (WattT; aliased by WheadT/WtailT after MQW)
    char*  R2     = base+off;
    u16*   WattTH = (u16*)  take(9437184);      // 3072*1536*2
    u16*   WattTL = (u16*)  take(9437184);
    size_t peak = off;
    if (peak > ws_size) return;   // fail loudly (out stays poisoned)

    // aliases
    u16* WpathTH = (u16*)R1;                        // 768*3072*2 = 4718592
    u16* WpathTL = (u16*)(R1 + 4718592);            // total 9437184 <= 10059776
    u16* WheadTH = (u16*)R2;                        // 768*2304*2 = 3538944
    u16* WheadTL = (u16*)(R2 + 3538944);
    u16* WtailTH = (u16*)(R2 + 7077888);
    u16* WtailTL = (u16*)(R2 + 10616832);           // total 14155776 <= 18874368
    u16* WbilTH  = (u16*)R0;                        // 128*49152*2 = 12582912
    u16* WbilTL  = (u16*)(R0 + 12582912);           // total 25165824 <= 42270720

    // ---- prep + conversions ----
    k_wsplit<<<dim3(3072/64, 1536/64, 1), 256, 0, stream>>>(Watt, WattTH, WattTL, 1536, 3072, 0, 0);
    k_wsplit<<<dim3(768/64, 512/64, NDOC), 256, 0, stream>>>(seq, seqTH, seqTL, 512, 768,
                                                             (long long)CL*DD, (long long)DD*CL);
    k_prep<<<NDOC*EE*MM + NDOC*EE, 256, 0, stream>>>(att, seq, ms, eatt, glob);
    k_pairvec<<<NPAIR, 256, 0, stream>>>(seq, eatt, ms, hts, nhH, nhL, ntH, ntL, paH, paL);

    gemm_f32s<<<dim3(12, 1, 2*NDOC), 256, 0, stream>>>(glob, Wm1, Wm2, Abuf, Bbuf);
    k_edge<<<NDOC*EE*EE, 256, 0, stream>>>(Abuf, Bbuf, bm, edge);
    k_outinit<<<(NPAIR*LOUT+255)/256, 256, 0, stream>>>(bbil, out);

    // rs = pa @ seq_i (MFMA, z=doc) -> rsH/L
    gemm_mfma<MRS,64,64><<<dim3(12, 6, NDOC), 256, 0, stream>>>(
        paH, paL, nullptr, nullptr, nullptr, nullptr, nullptr, nullptr,
        seqTH, seqTL, nullptr, nullptr, nullptr, nullptr,
        nullptr, rsH, rsL, nullptr, nullptr, PP, DD, CL, CL);

    // WpathT conversion (overwrites eatt/pa/seqT -- dead now)
    k_wsplit<<<dim3(768/64, 3072/64, 1), 256, 0, stream>>>(Wpath, WpathTH, WpathTL, 3072, 768, 0, 0);

    // qW = [nh|nt] @ Watt -> qWb (f32)
    gemm_mfma<MQW,128,128><<<dim3(3072/128, 12, 1), 256, 0, stream>>>(
        nhH, nhL, ntH, ntL, nullptr, nullptr, nullptr, nullptr,
        WattTH, WattTL, nullptr, nullptr, nullptr, nullptr,
        qWb, nullptr, nullptr, nullptr, nullptr, NPAIR, 3072, 1536, DD);

    // WheadT/WtailT conversions (overwrite WattT -- dead now)
    k_wsplit<<<dim3(768/64, 2304/64, 1), 256, 0, stream>>>(Whead, WheadTH, WheadTL, 2304, 768, 0, 0);
    k_wsplit<<<dim3(768/64, 2304/64, 1), 256, 0, stream>>>(Wtail, WtailTH, WtailTL, 2304, 768, 0, 0);

    k_scorepath<<<NPAIR, 256, 0, stream>>>(qWb, edge, hts, batt, pathcH, pathcL);

    // path = relu(pathc @ Wpath + bpath) -> pthH/L
    gemm_mfma<MSPLIT,64,64><<<dim3(12, 24, 1), 256, 0, stream>>>(
        pathcH, pathcL, nullptr, nullptr, nullptr, nullptr, nullptr, nullptr,
        WpathTH, WpathTL, nullptr, nullptr, bpath, nullptr,
        nullptr, pthH, pthL, nullptr, nullptr, NPAIR, DD, 3072, 3072);

    // WbilT conversion (overwrites edge/qWb/pathc -- dead now)
    k_wsplit<<<dim3(128/64, 49152/64, 1), 256, 0, stream>>>(Wbil, WbilTH, WbilTL, 49152, LOUT, 0, 0);

    // fused: hs = relu([nh|rs|path]@Whead+bhead) -> hsF (f32)
    //        ts = relu([nt|rs|path]@Wtail+btail) -> tsH/L (split)
    gemm_mfma<MHT,64,64><<<dim3(12, 24, 2), 256, 0, stream>>>(
        nhH, nhL, rsH, rsL, pthH, pthL, ntH, ntL,
        WheadTH, WheadTL, WtailTH, WtailTL, bhead, btail,
        hsF, nullptr, nullptr, tsH, tsL, NPAIR, DD, 2304, DD);

    // bilinear (factored): atomic accumulate into out
    k_bil2<<<dim3(1, 12, 48), 256, 0, stream>>>(tsH, tsL, hsF, WbilTH, WbilTL, out);
}